// Round 1
// baseline (1721.523 us; speedup 1.0000x reference)
//
#include <hip/hip_runtime.h>

#define NV   50000
#define FD   128
#define NE   800000
#define NOUT 64

// ---------------- preprocessing kernels ----------------

__global__ void zero_ints(int* __restrict__ p, int n) {
  int i = blockIdx.x * blockDim.x + threadIdx.x;
  if (i < n) p[i] = 0;
}

__global__ void count_deg(const int* __restrict__ row, const int* __restrict__ col,
                          int* __restrict__ cntS, int* __restrict__ cntD) {
  int e = blockIdx.x * blockDim.x + threadIdx.x;
  if (e < NE) {
    atomicAdd(&cntS[row[e]], 1);
    atomicAdd(&cntD[col[e]], 1);
  }
}

// dinv = deg>0 ? rsqrt(deg) : 0 ; homogeneous relations (r<2) get +1 self-loop
__global__ void compute_dinv(const int* __restrict__ cntS, const int* __restrict__ cntD,
                             float* __restrict__ dinvS, float* __restrict__ dinvD) {
  int r = blockIdx.y;
  int i = blockIdx.x * blockDim.x + threadIdx.x;
  if (i >= NV) return;
  int self = (r < 2) ? 1 : 0;
  float ds = (float)(cntS[r * NV + i] + self);
  float dd = (float)(cntD[r * NV + i] + self);
  dinvS[r * NV + i] = ds > 0.f ? rsqrtf(ds) : 0.f;
  dinvD[r * NV + i] = dd > 0.f ? rsqrtf(dd) : 0.f;
}

// exclusive prefix sum of in-degree counts -> rowptr ; one block per relation
__global__ __launch_bounds__(1024) void scan_rowptr(const int* __restrict__ cntD_all,
                                                    int* __restrict__ rowptr_all) {
  const int r = blockIdx.x;
  const int* cnt = cntD_all + r * NV;
  int* rowptr = rowptr_all + r * (NV + 1);
  const int t = threadIdx.x;
  const int C = (NV + 1023) / 1024;
  const int base = t * C;
  int sum = 0;
  for (int j = 0; j < C; ++j) {
    int idx = base + j;
    if (idx < NV) sum += cnt[idx];
  }
  __shared__ int sm[1024];
  sm[t] = sum;
  __syncthreads();
  for (int off = 1; off < 1024; off <<= 1) {
    int v = (t >= off) ? sm[t - off] : 0;
    __syncthreads();
    sm[t] += v;
    __syncthreads();
  }
  int run = (t == 0) ? 0 : sm[t - 1];
  for (int j = 0; j < C; ++j) {
    int idx = base + j;
    if (idx < NV) { rowptr[idx] = run; run += cnt[idx]; }
  }
  if (t == 1023) rowptr[NV] = run;  // == NE
}

__global__ void fill_csr(const int* __restrict__ row, const int* __restrict__ col,
                         const int* __restrict__ rowptr, int* __restrict__ cursor,
                         int* __restrict__ srcidx) {
  int e = blockIdx.x * blockDim.x + threadIdx.x;
  if (e < NE) {
    int c = col[e];
    int pos = rowptr[c] + atomicAdd(&cursor[c], 1);
    srcidx[pos] = row[e];
  }
}

// ---------------- dense GEMM: C[NV,128] = X[NV,128] @ W[128,128] ----------------
__global__ __launch_bounds__(256) void gemm128(const float* __restrict__ X,
                                               const float* __restrict__ W,
                                               float* __restrict__ C) {
  __shared__ float Xs[64][132];   // +4 pad: rows land on different banks
  __shared__ float Ws[128][128];  // reads are tx*4-strided -> 2-way (free)
  const int tid = threadIdx.x;
  const int row0 = blockIdx.x * 64;

  for (int i = tid * 4; i < 128 * 128; i += 1024) {
    float4 v = *(const float4*)(W + i);
    *(float4*)&Ws[i >> 7][i & 127] = v;
  }
  for (int i = tid * 4; i < 64 * 128; i += 1024) {
    int rr = i >> 7, cc = i & 127;
    int gr = row0 + rr;
    float4 v = make_float4(0.f, 0.f, 0.f, 0.f);
    if (gr < NV) v = *(const float4*)(X + (size_t)gr * FD + cc);
    *(float4*)&Xs[rr][cc] = v;
  }
  __syncthreads();

  const int tx = tid & 15, ty = tid >> 4;  // 16 col-groups x 16 row-groups
  float acc[4][8];
  #pragma unroll
  for (int i = 0; i < 4; ++i)
    #pragma unroll
    for (int j = 0; j < 8; ++j) acc[i][j] = 0.f;

  for (int k = 0; k < 128; k += 4) {
    float4 xr[4], wa[4], wb[4];
    #pragma unroll
    for (int i = 0; i < 4; ++i) xr[i] = *(const float4*)&Xs[ty * 4 + i][k];
    #pragma unroll
    for (int j = 0; j < 4; ++j) {
      wa[j] = *(const float4*)&Ws[k + j][tx * 4];
      wb[j] = *(const float4*)&Ws[k + j][64 + tx * 4];
    }
    #pragma unroll
    for (int i = 0; i < 4; ++i) {
      const float* xv = (const float*)&xr[i];
      #pragma unroll
      for (int j = 0; j < 4; ++j) {
        float x = xv[j];
        acc[i][0] = fmaf(x, wa[j].x, acc[i][0]);
        acc[i][1] = fmaf(x, wa[j].y, acc[i][1]);
        acc[i][2] = fmaf(x, wa[j].z, acc[i][2]);
        acc[i][3] = fmaf(x, wa[j].w, acc[i][3]);
        acc[i][4] = fmaf(x, wb[j].x, acc[i][4]);
        acc[i][5] = fmaf(x, wb[j].y, acc[i][5]);
        acc[i][6] = fmaf(x, wb[j].z, acc[i][6]);
        acc[i][7] = fmaf(x, wb[j].w, acc[i][7]);
      }
    }
  }
  #pragma unroll
  for (int i = 0; i < 4; ++i) {
    int gr = row0 + ty * 4 + i;
    if (gr < NV) {
      *(float4*)(C + (size_t)gr * FD + tx * 4) =
          make_float4(acc[i][0], acc[i][1], acc[i][2], acc[i][3]);
      *(float4*)(C + (size_t)gr * FD + 64 + tx * 4) =
          make_float4(acc[i][4], acc[i][5], acc[i][6], acc[i][7]);
    }
  }
}

// ---------------- fused pull aggregation for one destination node type ----------
// Y[i,:] = relu( dDA[i]*( dSA[i]*hA[i,:] + sum_{s in CSR_A(i)} dSA[s]*hA[s,:] )
//             + dDB[i]*(                   sum_{s in CSR_B(i)} dSB[s]*hB[s,:] )
//             + bA + bB )
// one wave per node, each lane owns 2 feature dims
__global__ __launch_bounds__(256) void pull2(
    const float* __restrict__ hA, const int* __restrict__ rpA, const int* __restrict__ srcA,
    const float* __restrict__ dSA, const float* __restrict__ dDA,
    const float* __restrict__ hB, const int* __restrict__ rpB, const int* __restrict__ srcB,
    const float* __restrict__ dSB, const float* __restrict__ dDB,
    const float* __restrict__ bA, const float* __restrict__ bB,
    float* __restrict__ Y) {
  const int i = (blockIdx.x * 256 + threadIdx.x) >> 6;
  const int lane = threadIdx.x & 63;
  if (i >= NV) return;
  const int d = lane * 2;

  float ax, ay;
  {  // self-loop term (relation A is always homogeneous)
    float w = dSA[i];
    float2 v = *(const float2*)(hA + (size_t)i * FD + d);
    ax = w * v.x; ay = w * v.y;
  }
  int p0 = rpA[i], p1 = rpA[i + 1];
  for (int p = p0; p < p1; ++p) {
    int s = srcA[p];
    float w = dSA[s];
    float2 v = *(const float2*)(hA + (size_t)s * FD + d);
    ax = fmaf(w, v.x, ax); ay = fmaf(w, v.y, ay);
  }
  float bxs = 0.f, bys = 0.f;
  p0 = rpB[i]; p1 = rpB[i + 1];
  for (int p = p0; p < p1; ++p) {
    int s = srcB[p];
    float w = dSB[s];
    float2 v = *(const float2*)(hB + (size_t)s * FD + d);
    bxs = fmaf(w, v.x, bxs); bys = fmaf(w, v.y, bys);
  }
  float wA = dDA[i], wB = dDB[i];
  float ox = ax * wA + bxs * wB + bA[d] + bB[d];
  float oy = ay * wA + bys * wB + bA[d + 1] + bB[d + 1];
  Y[(size_t)i * FD + d]     = fmaxf(ox, 0.f);
  Y[(size_t)i * FD + d + 1] = fmaxf(oy, 0.f);
}

// ---------------- final linear: Out[NV,64] = X[NV,128] @ lw^T + lb --------------
__global__ __launch_bounds__(256) void linear64(const float* __restrict__ X,
                                                const float* __restrict__ lw,
                                                const float* __restrict__ lb,
                                                float* __restrict__ Out) {
  __shared__ float Wt[128][68];  // Wt[h][o] = lw[o][h], +4 pad
  __shared__ float Xs[64][132];
  const int tid = threadIdx.x;
  const int row0 = blockIdx.x * 64;

  for (int i = tid * 4; i < 64 * 128; i += 1024) {
    float4 v = *(const float4*)(lw + i);
    int o = i >> 7, h = i & 127;
    Wt[h + 0][o] = v.x; Wt[h + 1][o] = v.y; Wt[h + 2][o] = v.z; Wt[h + 3][o] = v.w;
  }
  for (int i = tid * 4; i < 64 * 128; i += 1024) {
    int rr = i >> 7, cc = i & 127;
    int gr = row0 + rr;
    float4 v = make_float4(0.f, 0.f, 0.f, 0.f);
    if (gr < NV) v = *(const float4*)(X + (size_t)gr * FD + cc);
    *(float4*)&Xs[rr][cc] = v;
  }
  __syncthreads();

  const int tx = tid & 15, ty = tid >> 4;
  float acc[4][4];
  #pragma unroll
  for (int i = 0; i < 4; ++i)
    #pragma unroll
    for (int j = 0; j < 4; ++j) acc[i][j] = 0.f;

  for (int k = 0; k < 128; k += 4) {
    float4 xr[4], w[4];
    #pragma unroll
    for (int i = 0; i < 4; ++i) xr[i] = *(const float4*)&Xs[ty * 4 + i][k];
    #pragma unroll
    for (int j = 0; j < 4; ++j) w[j] = *(const float4*)&Wt[k + j][tx * 4];
    #pragma unroll
    for (int i = 0; i < 4; ++i) {
      const float* xv = (const float*)&xr[i];
      #pragma unroll
      for (int j = 0; j < 4; ++j) {
        float x = xv[j];
        acc[i][0] = fmaf(x, w[j].x, acc[i][0]);
        acc[i][1] = fmaf(x, w[j].y, acc[i][1]);
        acc[i][2] = fmaf(x, w[j].z, acc[i][2]);
        acc[i][3] = fmaf(x, w[j].w, acc[i][3]);
      }
    }
  }
  float4 bias = *(const float4*)(lb + tx * 4);
  #pragma unroll
  for (int i = 0; i < 4; ++i) {
    int gr = row0 + ty * 4 + i;
    if (gr < NV) {
      *(float4*)(Out + (size_t)gr * NOUT + tx * 4) =
          make_float4(acc[i][0] + bias.x, acc[i][1] + bias.y,
                      acc[i][2] + bias.z, acc[i][3] + bias.w);
    }
  }
}

// ---------------- host orchestration ----------------

extern "C" void kernel_launch(void* const* d_in, const int* in_sizes, int n_in,
                              void* d_out, int out_size, void* d_ws, size_t ws_size,
                              hipStream_t stream) {
  const float* x_drug = (const float*)d_in[0];
  const float* x_dis  = (const float*)d_in[1];
  const int* ei[4] = { (const int*)d_in[2], (const int*)d_in[3],
                       (const int*)d_in[4], (const int*)d_in[5] };  // dd, ss, ds, sd
  const float* Ws = (const float*)d_in[6];
  const float* bs = (const float*)d_in[7];
  const float* lw = (const float*)d_in[8];
  const float* lb = (const float*)d_in[9];
  float* out = (float*)d_out;

  // workspace carve (~171 MB)
  char* p = (char*)d_ws;
  auto take = [&](size_t bytes) -> void* {
    char* q = p;
    p += (bytes + 255) & ~(size_t)255;
    return (void*)q;
  };
  int* cnt_all = (int*)take((size_t)12 * NV * sizeof(int));
  int* cntS = cnt_all;
  int* cntD = cnt_all + 4 * NV;
  int* cursor = cnt_all + 8 * NV;
  int* rowptr = (int*)take((size_t)4 * (NV + 1) * sizeof(int));
  int* srcidx = (int*)take((size_t)4 * NE * sizeof(int));
  float* dinvS = (float*)take((size_t)4 * NV * sizeof(float));
  float* dinvD = (float*)take((size_t)4 * NV * sizeof(float));
  float* hA  = (float*)take((size_t)NV * FD * sizeof(float));
  float* hB  = (float*)take((size_t)NV * FD * sizeof(float));
  float* XD1 = (float*)take((size_t)NV * FD * sizeof(float));
  float* XS1 = (float*)take((size_t)NV * FD * sizeof(float));
  float* XD2 = (float*)take((size_t)NV * FD * sizeof(float));
  float* XS2 = (float*)take((size_t)NV * FD * sizeof(float));

  // ---- edge-structure prep (shared across layers) ----
  zero_ints<<<(12 * NV + 255) / 256, 256, 0, stream>>>(cnt_all, 12 * NV);
  for (int r = 0; r < 4; ++r)
    count_deg<<<(NE + 255) / 256, 256, 0, stream>>>(ei[r], ei[r] + NE,
                                                    cntS + r * NV, cntD + r * NV);
  compute_dinv<<<dim3((NV + 255) / 256, 4), 256, 0, stream>>>(cntS, cntD, dinvS, dinvD);
  scan_rowptr<<<4, 1024, 0, stream>>>(cntD, rowptr);
  for (int r = 0; r < 4; ++r)
    fill_csr<<<(NE + 255) / 256, 256, 0, stream>>>(ei[r], ei[r] + NE,
                                                   rowptr + r * (NV + 1),
                                                   cursor + r * NV,
                                                   srcidx + (size_t)r * NE);

  // ---- layers ----
  const int GEMM_GRID = (NV + 63) / 64;   // 782
  const int PULL_GRID = NV * 64 / 256;    // 12500
  const float* xd = x_drug;
  const float* xs = x_dis;
  float* nextd[2] = {XD1, XD2};
  float* nexts[2] = {XS1, XS2};
  for (int l = 0; l < 2; ++l) {
    const float* W0 = Ws + (size_t)(l * 4 + 0) * FD * FD;
    const float* W1 = Ws + (size_t)(l * 4 + 1) * FD * FD;
    const float* W2 = Ws + (size_t)(l * 4 + 2) * FD * FD;
    const float* W3 = Ws + (size_t)(l * 4 + 3) * FD * FD;
    const float* b0 = bs + (l * 4 + 0) * FD;
    const float* b1 = bs + (l * 4 + 1) * FD;
    const float* b2 = bs + (l * 4 + 2) * FD;
    const float* b3 = bs + (l * 4 + 3) * FD;

    // drug_new = gcn(x_drug, dd, W0) + gcn(x_dis, sd, W3)
    gemm128<<<GEMM_GRID, 256, 0, stream>>>(xd, W0, hA);
    gemm128<<<GEMM_GRID, 256, 0, stream>>>(xs, W3, hB);
    pull2<<<PULL_GRID, 256, 0, stream>>>(
        hA, rowptr + 0 * (NV + 1), srcidx + (size_t)0 * NE, dinvS + 0 * NV, dinvD + 0 * NV,
        hB, rowptr + 3 * (NV + 1), srcidx + (size_t)3 * NE, dinvS + 3 * NV, dinvD + 3 * NV,
        b0, b3, nextd[l]);

    // dis_new = gcn(x_dis, ss, W1) + gcn(x_drug, ds, W2)
    gemm128<<<GEMM_GRID, 256, 0, stream>>>(xs, W1, hA);
    gemm128<<<GEMM_GRID, 256, 0, stream>>>(xd, W2, hB);
    pull2<<<PULL_GRID, 256, 0, stream>>>(
        hA, rowptr + 1 * (NV + 1), srcidx + (size_t)1 * NE, dinvS + 1 * NV, dinvD + 1 * NV,
        hB, rowptr + 2 * (NV + 1), srcidx + (size_t)2 * NE, dinvS + 2 * NV, dinvD + 2 * NV,
        b1, b2, nexts[l]);

    xd = nextd[l];
    xs = nexts[l];
  }

  // ---- final linear ----
  linear64<<<GEMM_GRID, 256, 0, stream>>>(xd, lw, lb, out);
  linear64<<<GEMM_GRID, 256, 0, stream>>>(xs, lw, lb, out + (size_t)NV * NOUT);
}

// Round 2
// 1118.537 us; speedup vs baseline: 1.5391x; 1.5391x over previous
//
#include <hip/hip_runtime.h>

#define NV   50000
#define FD   128
#define NE   800000
#define NOUT 64

typedef unsigned short bf16_t;

__device__ __forceinline__ bf16_t f2bf(float f) {
  unsigned u = __builtin_bit_cast(unsigned, f);
  return (bf16_t)((u + 0x7fffu + ((u >> 16) & 1u)) >> 16);
}
__device__ __forceinline__ float bflo(unsigned v) {  // low ushort -> float
  return __builtin_bit_cast(float, v << 16);
}
__device__ __forceinline__ float bfhi(unsigned v) {  // high ushort -> float
  return __builtin_bit_cast(float, v & 0xffff0000u);
}

struct Ptr4 { const int* p[4]; };

// ---------------- preprocessing kernels ----------------

__global__ void zero_ints(int* __restrict__ p, int n) {
  int i = blockIdx.x * blockDim.x + threadIdx.x;
  if (i < n) p[i] = 0;
}

__global__ void count_deg4(Ptr4 rows, Ptr4 cols,
                           int* __restrict__ cntS, int* __restrict__ cntD) {
  int r = blockIdx.y;
  int e = blockIdx.x * blockDim.x + threadIdx.x;
  if (e < NE) {
    atomicAdd(&cntS[r * NV + rows.p[r][e]], 1);
    atomicAdd(&cntD[r * NV + cols.p[r][e]], 1);
  }
}

// dinv = deg>0 ? rsqrt(deg) : 0 ; homogeneous relations (r<2) get +1 self-loop
__global__ void compute_dinv(const int* __restrict__ cntS, const int* __restrict__ cntD,
                             float* __restrict__ dinvS, float* __restrict__ dinvD) {
  int r = blockIdx.y;
  int i = blockIdx.x * blockDim.x + threadIdx.x;
  if (i >= NV) return;
  int self = (r < 2) ? 1 : 0;
  float ds = (float)(cntS[r * NV + i] + self);
  float dd = (float)(cntD[r * NV + i] + self);
  dinvS[r * NV + i] = ds > 0.f ? rsqrtf(ds) : 0.f;
  dinvD[r * NV + i] = dd > 0.f ? rsqrtf(dd) : 0.f;
}

// exclusive prefix sum of in-degree counts -> rowptr ; one block per relation
__global__ __launch_bounds__(1024) void scan_rowptr(const int* __restrict__ cntD_all,
                                                    int* __restrict__ rowptr_all) {
  const int r = blockIdx.x;
  const int* cnt = cntD_all + r * NV;
  int* rowptr = rowptr_all + r * (NV + 1);
  const int t = threadIdx.x;
  const int C = (NV + 1023) / 1024;
  const int base = t * C;
  int sum = 0;
  for (int j = 0; j < C; ++j) {
    int idx = base + j;
    if (idx < NV) sum += cnt[idx];
  }
  __shared__ int sm[1024];
  sm[t] = sum;
  __syncthreads();
  for (int off = 1; off < 1024; off <<= 1) {
    int v = (t >= off) ? sm[t - off] : 0;
    __syncthreads();
    sm[t] += v;
    __syncthreads();
  }
  int run = (t == 0) ? 0 : sm[t - 1];
  for (int j = 0; j < C; ++j) {
    int idx = base + j;
    if (idx < NV) { rowptr[idx] = run; run += cnt[idx]; }
  }
  if (t == 1023) rowptr[NV] = run;  // == NE
}

__global__ void fill_csr4(Ptr4 rows, Ptr4 cols, const int* __restrict__ rowptr_all,
                          int* __restrict__ cursor_all, int* __restrict__ srcidx_all) {
  int r = blockIdx.y;
  int e = blockIdx.x * blockDim.x + threadIdx.x;
  if (e < NE) {
    int c = cols.p[r][e];
    int pos = rowptr_all[r * (NV + 1) + c] + atomicAdd(&cursor_all[r * NV + c], 1);
    srcidx_all[(size_t)r * NE + pos] = rows.p[r][e];
  }
}

// ---------------- dual GEMM: H[r,:] = bf16( dS[r] * (X[r,:] @ W) ) ----------------
// 128x128 tile, K streamed in 32-chunks. LDS ~34KB -> 4 blocks/CU.
// blockIdx.y selects which of two independent (X,W,dS,H) problems.
__global__ __launch_bounds__(256) void gemm_dual(
    const float* __restrict__ X0, const float* __restrict__ W0,
    const float* __restrict__ dS0, bf16_t* __restrict__ H0,
    const float* __restrict__ X1, const float* __restrict__ W1,
    const float* __restrict__ dS1, bf16_t* __restrict__ H1) {
  const float* X; const float* W; const float* dS; bf16_t* H;
  if (blockIdx.y == 0) { X = X0; W = W0; dS = dS0; H = H0; }
  else                 { X = X1; W = W1; dS = dS1; H = H1; }

  __shared__ float Xs[128][33];   // stride 33: scalar reads conflict-free (banks r+k mod 32)
  __shared__ float Wk[32][132];   // stride 132 (16B-aligned); float4 reads 2-way (free)
  const int tid = threadIdx.x;
  const int row0 = blockIdx.x * 128;
  const int tx = tid & 15, ty = tid >> 4;

  float acc[8][8] = {};

  for (int kc = 0; kc < FD; kc += 32) {
    __syncthreads();
    // stage X chunk: 128 rows x 32 k  (scalar LDS writes; 2-way banks, free)
    #pragma unroll
    for (int j = 0; j < 4; ++j) {
      int idx = tid + j * 256;              // 0..1023
      int r = idx >> 3, c = (idx & 7) * 4;
      float4 v = make_float4(0.f, 0.f, 0.f, 0.f);
      int gr = row0 + r;
      if (gr < NV) v = *(const float4*)(X + (size_t)gr * FD + kc + c);
      Xs[r][c + 0] = v.x; Xs[r][c + 1] = v.y; Xs[r][c + 2] = v.z; Xs[r][c + 3] = v.w;
    }
    // stage W chunk: 32 k x 128 cols
    #pragma unroll
    for (int j = 0; j < 4; ++j) {
      int idx = tid + j * 256;
      int r = idx >> 5, c = (idx & 31) * 4;
      float4 v = *(const float4*)(W + (size_t)(kc + r) * FD + c);
      *(float4*)&Wk[r][c] = v;
    }
    __syncthreads();

    #pragma unroll
    for (int k = 0; k < 32; ++k) {
      float xv[8];
      #pragma unroll
      for (int i = 0; i < 8; ++i) xv[i] = Xs[ty * 8 + i][k];
      float4 wa = *(const float4*)&Wk[k][tx * 4];
      float4 wb = *(const float4*)&Wk[k][64 + tx * 4];
      #pragma unroll
      for (int i = 0; i < 8; ++i) {
        acc[i][0] = fmaf(xv[i], wa.x, acc[i][0]);
        acc[i][1] = fmaf(xv[i], wa.y, acc[i][1]);
        acc[i][2] = fmaf(xv[i], wa.z, acc[i][2]);
        acc[i][3] = fmaf(xv[i], wa.w, acc[i][3]);
        acc[i][4] = fmaf(xv[i], wb.x, acc[i][4]);
        acc[i][5] = fmaf(xv[i], wb.y, acc[i][5]);
        acc[i][6] = fmaf(xv[i], wb.z, acc[i][6]);
        acc[i][7] = fmaf(xv[i], wb.w, acc[i][7]);
      }
    }
  }

  // epilogue: scale by dS[row], round to bf16, store 2x 8B
  #pragma unroll
  for (int i = 0; i < 8; ++i) {
    int r = row0 + ty * 8 + i;
    if (r < NV) {
      float s = dS[r];
      unsigned a0 = (unsigned)f2bf(acc[i][0] * s) | ((unsigned)f2bf(acc[i][1] * s) << 16);
      unsigned a1 = (unsigned)f2bf(acc[i][2] * s) | ((unsigned)f2bf(acc[i][3] * s) << 16);
      unsigned b0 = (unsigned)f2bf(acc[i][4] * s) | ((unsigned)f2bf(acc[i][5] * s) << 16);
      unsigned b1 = (unsigned)f2bf(acc[i][6] * s) | ((unsigned)f2bf(acc[i][7] * s) << 16);
      *(uint2*)(H + (size_t)r * FD + tx * 4)      = make_uint2(a0, a1);
      *(uint2*)(H + (size_t)r * FD + 64 + tx * 4) = make_uint2(b0, b1);
    }
  }
}

// ---------------- fused pull aggregation ----------------
// h rows are bf16, pre-scaled by dS. One wave per node; lane owns 2 dims.
// 4x-unrolled gather: batch index loads then row loads -> MLP ~4.
__device__ __forceinline__ void gather_acc(const bf16_t* __restrict__ h,
                                           const int* __restrict__ src,
                                           int p0, int p1, int d,
                                           float& ax, float& ay) {
  int p = p0;
  for (; p + 4 <= p1; p += 4) {
    int s0 = src[p], s1 = src[p + 1], s2 = src[p + 2], s3 = src[p + 3];
    unsigned v0 = *(const unsigned*)(h + ((size_t)s0 << 7) + d);
    unsigned v1 = *(const unsigned*)(h + ((size_t)s1 << 7) + d);
    unsigned v2 = *(const unsigned*)(h + ((size_t)s2 << 7) + d);
    unsigned v3 = *(const unsigned*)(h + ((size_t)s3 << 7) + d);
    ax += bflo(v0); ay += bfhi(v0);
    ax += bflo(v1); ay += bfhi(v1);
    ax += bflo(v2); ay += bfhi(v2);
    ax += bflo(v3); ay += bfhi(v3);
  }
  for (; p < p1; ++p) {
    int s = src[p];
    unsigned v = *(const unsigned*)(h + ((size_t)s << 7) + d);
    ax += bflo(v); ay += bfhi(v);
  }
}

__global__ __launch_bounds__(256) void pull2(
    const bf16_t* __restrict__ hA, const int* __restrict__ rpA, const int* __restrict__ srcA,
    const float* __restrict__ dDA,
    const bf16_t* __restrict__ hB, const int* __restrict__ rpB, const int* __restrict__ srcB,
    const float* __restrict__ dDB,
    const float* __restrict__ bA, const float* __restrict__ bB,
    float* __restrict__ Y) {
  const int i = (blockIdx.x * 256 + threadIdx.x) >> 6;
  const int lane = threadIdx.x & 63;
  if (i >= NV) return;
  const int d = lane * 2;

  float ax, ay;
  {  // self-loop term (relation A is homogeneous; h already dS-scaled)
    unsigned v = *(const unsigned*)(hA + ((size_t)i << 7) + d);
    ax = bflo(v); ay = bfhi(v);
  }
  gather_acc(hA, srcA, rpA[i], rpA[i + 1], d, ax, ay);
  float bx = 0.f, by = 0.f;
  gather_acc(hB, srcB, rpB[i], rpB[i + 1], d, bx, by);

  float wA = dDA[i], wB = dDB[i];
  float ox = fmaf(ax, wA, fmaf(bx, wB, bA[d] + bB[d]));
  float oy = fmaf(ay, wA, fmaf(by, wB, bA[d + 1] + bB[d + 1]));
  *(float2*)(Y + (size_t)i * FD + d) = make_float2(fmaxf(ox, 0.f), fmaxf(oy, 0.f));
}

// ---------------- final linear: Out[NV,64] = X[NV,128] @ lw^T + lb --------------
__global__ __launch_bounds__(256) void linear64(const float* __restrict__ X,
                                                const float* __restrict__ lw,
                                                const float* __restrict__ lb,
                                                float* __restrict__ Out) {
  __shared__ float Wt[128][68];  // Wt[h][o] = lw[o][h]
  __shared__ float Xs[64][132];
  const int tid = threadIdx.x;
  const int row0 = blockIdx.x * 64;

  for (int i = tid * 4; i < 64 * 128; i += 1024) {
    float4 v = *(const float4*)(lw + i);
    int o = i >> 7, h = i & 127;
    Wt[h + 0][o] = v.x; Wt[h + 1][o] = v.y; Wt[h + 2][o] = v.z; Wt[h + 3][o] = v.w;
  }
  for (int i = tid * 4; i < 64 * 128; i += 1024) {
    int rr = i >> 7, cc = i & 127;
    int gr = row0 + rr;
    float4 v = make_float4(0.f, 0.f, 0.f, 0.f);
    if (gr < NV) v = *(const float4*)(X + (size_t)gr * FD + cc);
    *(float4*)&Xs[rr][cc] = v;
  }
  __syncthreads();

  const int tx = tid & 15, ty = tid >> 4;
  float acc[4][4];
  #pragma unroll
  for (int i = 0; i < 4; ++i)
    #pragma unroll
    for (int j = 0; j < 4; ++j) acc[i][j] = 0.f;

  for (int k = 0; k < 128; k += 4) {
    float4 xr[4], w[4];
    #pragma unroll
    for (int i = 0; i < 4; ++i) xr[i] = *(const float4*)&Xs[ty * 4 + i][k];
    #pragma unroll
    for (int j = 0; j < 4; ++j) w[j] = *(const float4*)&Wt[k + j][tx * 4];
    #pragma unroll
    for (int i = 0; i < 4; ++i) {
      const float* xv = (const float*)&xr[i];
      #pragma unroll
      for (int j = 0; j < 4; ++j) {
        float x = xv[j];
        acc[i][0] = fmaf(x, w[j].x, acc[i][0]);
        acc[i][1] = fmaf(x, w[j].y, acc[i][1]);
        acc[i][2] = fmaf(x, w[j].z, acc[i][2]);
        acc[i][3] = fmaf(x, w[j].w, acc[i][3]);
      }
    }
  }
  float4 bias = *(const float4*)(lb + tx * 4);
  #pragma unroll
  for (int i = 0; i < 4; ++i) {
    int gr = row0 + ty * 4 + i;
    if (gr < NV) {
      *(float4*)(Out + (size_t)gr * NOUT + tx * 4) =
          make_float4(acc[i][0] + bias.x, acc[i][1] + bias.y,
                      acc[i][2] + bias.z, acc[i][3] + bias.w);
    }
  }
}

// ---------------- host orchestration ----------------

extern "C" void kernel_launch(void* const* d_in, const int* in_sizes, int n_in,
                              void* d_out, int out_size, void* d_ws, size_t ws_size,
                              hipStream_t stream) {
  const float* x_drug = (const float*)d_in[0];
  const float* x_dis  = (const float*)d_in[1];
  const int* ei[4] = { (const int*)d_in[2], (const int*)d_in[3],
                       (const int*)d_in[4], (const int*)d_in[5] };  // dd, ss, ds, sd
  const float* Ws = (const float*)d_in[6];
  const float* bs = (const float*)d_in[7];
  const float* lw = (const float*)d_in[8];
  const float* lb = (const float*)d_in[9];
  float* out = (float*)d_out;

  // workspace carve
  char* p = (char*)d_ws;
  auto take = [&](size_t bytes) -> void* {
    char* q = p;
    p += (bytes + 255) & ~(size_t)255;
    return (void*)q;
  };
  int* cnt_all = (int*)take((size_t)12 * NV * sizeof(int));
  int* cntS = cnt_all;
  int* cntD = cnt_all + 4 * NV;
  int* cursor = cnt_all + 8 * NV;
  int* rowptr = (int*)take((size_t)4 * (NV + 1) * sizeof(int));
  int* srcidx = (int*)take((size_t)4 * NE * sizeof(int));
  float* dinvS = (float*)take((size_t)4 * NV * sizeof(float));
  float* dinvD = (float*)take((size_t)4 * NV * sizeof(float));
  bf16_t* hA = (bf16_t*)take((size_t)NV * FD * sizeof(bf16_t));
  bf16_t* hB = (bf16_t*)take((size_t)NV * FD * sizeof(bf16_t));
  float* XD1 = (float*)take((size_t)NV * FD * sizeof(float));
  float* XS1 = (float*)take((size_t)NV * FD * sizeof(float));
  float* XD2 = (float*)take((size_t)NV * FD * sizeof(float));
  float* XS2 = (float*)take((size_t)NV * FD * sizeof(float));

  Ptr4 rows = {{ ei[0], ei[1], ei[2], ei[3] }};
  Ptr4 cols = {{ ei[0] + NE, ei[1] + NE, ei[2] + NE, ei[3] + NE }};

  // ---- edge-structure prep (shared across layers) ----
  zero_ints<<<(12 * NV + 255) / 256, 256, 0, stream>>>(cnt_all, 12 * NV);
  count_deg4<<<dim3((NE + 255) / 256, 4), 256, 0, stream>>>(rows, cols, cntS, cntD);
  compute_dinv<<<dim3((NV + 255) / 256, 4), 256, 0, stream>>>(cntS, cntD, dinvS, dinvD);
  scan_rowptr<<<4, 1024, 0, stream>>>(cntD, rowptr);
  fill_csr4<<<dim3((NE + 255) / 256, 4), 256, 0, stream>>>(rows, cols, rowptr, cursor, srcidx);

  // ---- layers ----
  const dim3 GEMM_GRID((NV + 127) / 128, 2);  // 391 x 2
  const int PULL_GRID = NV * 64 / 256;        // 12500
  const int LIN_GRID = (NV + 63) / 64;
  const float* xd = x_drug;
  const float* xs = x_dis;
  float* nextd[2] = {XD1, XD2};
  float* nexts[2] = {XS1, XS2};
  for (int l = 0; l < 2; ++l) {
    const float* W0 = Ws + (size_t)(l * 4 + 0) * FD * FD;
    const float* W1 = Ws + (size_t)(l * 4 + 1) * FD * FD;
    const float* W2 = Ws + (size_t)(l * 4 + 2) * FD * FD;
    const float* W3 = Ws + (size_t)(l * 4 + 3) * FD * FD;
    const float* b0 = bs + (l * 4 + 0) * FD;
    const float* b1 = bs + (l * 4 + 1) * FD;
    const float* b2 = bs + (l * 4 + 2) * FD;
    const float* b3 = bs + (l * 4 + 3) * FD;

    // drug_new = gcn(x_drug, dd, W0) + gcn(x_dis, sd, W3)
    gemm_dual<<<GEMM_GRID, 256, 0, stream>>>(xd, W0, dinvS + 0 * NV, hA,
                                             xs, W3, dinvS + 3 * NV, hB);
    pull2<<<PULL_GRID, 256, 0, stream>>>(
        hA, rowptr + 0 * (NV + 1), srcidx + (size_t)0 * NE, dinvD + 0 * NV,
        hB, rowptr + 3 * (NV + 1), srcidx + (size_t)3 * NE, dinvD + 3 * NV,
        b0, b3, nextd[l]);

    // dis_new = gcn(x_dis, ss, W1) + gcn(x_drug, ds, W2)
    gemm_dual<<<GEMM_GRID, 256, 0, stream>>>(xs, W1, dinvS + 1 * NV, hA,
                                             xd, W2, dinvS + 2 * NV, hB);
    pull2<<<PULL_GRID, 256, 0, stream>>>(
        hA, rowptr + 1 * (NV + 1), srcidx + (size_t)1 * NE, dinvD + 1 * NV,
        hB, rowptr + 2 * (NV + 1), srcidx + (size_t)2 * NE, dinvD + 2 * NV,
        b1, b2, nexts[l]);

    xd = nextd[l];
    xs = nexts[l];
  }

  // ---- final linear ----
  linear64<<<LIN_GRID, 256, 0, stream>>>(xd, lw, lb, out);
  linear64<<<LIN_GRID, 256, 0, stream>>>(xs, lw, lb, out + (size_t)NV * NOUT);
}

// Round 3
// 794.450 us; speedup vs baseline: 2.1669x; 1.4079x over previous
//
#include <hip/hip_runtime.h>

#define NV   50000
#define FD   128
#define NE   800000
#define NOUT 64
#define NBIN 196          // ceil(NV/256) coarse buckets of 256 nodes
#define CH   2048         // edges per block in P0/P1
#define NBLK 391          // ceil(NE/CH)
#define SCAN_L (NBIN * NBLK)
#define CAP2 12288        // LDS staging cap in P2 (avg span ~4083)

typedef unsigned short bf16_t;
typedef unsigned short u16;
typedef unsigned char  u8;

__device__ __forceinline__ bf16_t f2bf(float f) {
  unsigned u = __builtin_bit_cast(unsigned, f);
  return (bf16_t)((u + 0x7fffu + ((u >> 16) & 1u)) >> 16);
}
__device__ __forceinline__ float bflo(unsigned v) { return __builtin_bit_cast(float, v << 16); }
__device__ __forceinline__ float bfhi(unsigned v) { return __builtin_bit_cast(float, v & 0xffff0000u); }

struct Ptr4 { const int* p[4]; };

// ================= bucket-sort based CSR build (no global atomics) =================

// P0: per-(block,bin) histograms of dst and src, via LDS atomics
__global__ __launch_bounds__(256) void p0_hist(Ptr4 rows, Ptr4 cols,
                                               int* __restrict__ blockCnt) {
  const int r = blockIdx.y, blk = blockIdx.x, t = threadIdx.x;
  __shared__ int cd[NBIN], cs[NBIN];
  for (int i = t; i < NBIN; i += 256) { cd[i] = 0; cs[i] = 0; }
  __syncthreads();
  const int e0 = blk * CH;
  const int n = min(CH, NE - e0);
  const int* rw = rows.p[r] + e0;
  const int* cl = cols.p[r] + e0;
  for (int i = t; i < n; i += 256) {
    atomicAdd(&cd[cl[i] >> 8], 1);
    atomicAdd(&cs[rw[i] >> 8], 1);
  }
  __syncthreads();
  int* bd = blockCnt + (size_t)(r * 2 + 0) * SCAN_L;
  int* bs = blockCnt + (size_t)(r * 2 + 1) * SCAN_L;
  for (int i = t; i < NBIN; i += 256) {
    bd[i * NBLK + blk] = cd[i];
    bs[i * NBLK + blk] = cs[i];
  }
}

// exclusive scan of each (relation,side) window -> per-(block,bin) bases + bucket bases
__global__ __launch_bounds__(1024) void p_scan(int* __restrict__ blockCnt,
                                               int* __restrict__ bucketBase) {
  const int r2 = blockIdx.x;           // 0..7 = r*2+side
  int* a = blockCnt + (size_t)r2 * SCAN_L;
  const int t = threadIdx.x;
  const int C = (SCAN_L + 1023) / 1024;  // 75
  int s = 0;
  for (int j = 0; j < C; ++j) {
    int idx = t * C + j;
    if (idx < SCAN_L) s += a[idx];
  }
  __shared__ int sm[1024];
  sm[t] = s;
  __syncthreads();
  for (int off = 1; off < 1024; off <<= 1) {
    int v = (t >= off) ? sm[t - off] : 0;
    __syncthreads();
    sm[t] += v;
    __syncthreads();
  }
  int run = (t == 0) ? 0 : sm[t - 1];
  for (int j = 0; j < C; ++j) {
    int idx = t * C + j;
    if (idx < SCAN_L) {
      int v = a[idx];
      a[idx] = run;
      if (idx % NBLK == 0) bucketBase[r2 * (NBIN + 1) + idx / NBLK] = run;
      run += v;
    }
  }
  if (t == 0) bucketBase[r2 * (NBIN + 1) + NBIN] = NE;
}

// P1: scatter edges into dst-buckets (packed pairs) and src-buckets (u8 locals),
// LDS-reordered for coalesced output; positions fully precomputed (deterministic)
__global__ __launch_bounds__(256) void p1_scatter(Ptr4 rows, Ptr4 cols,
                                                  const int* __restrict__ blockCnt,
                                                  unsigned* __restrict__ pairD,
                                                  u8* __restrict__ srcb) {
  const int r = blockIdx.y, blk = blockIdx.x, t = threadIdx.x;
  const int e0 = blk * CH;
  const int n = min(CH, NE - e0);
  const int* rw = rows.p[r] + e0;
  const int* cl = cols.p[r] + e0;

  __shared__ int cnt[256], sc[256], lofs[256], cnt2[256], baseT[256];
  __shared__ unsigned pr[CH];
  __shared__ u8 binb[CH];
  __shared__ u8 pay8[CH];

  // ---------- dst side ----------
  cnt[t] = 0; cnt2[t] = 0;
  __syncthreads();
  for (int i = t; i < n; i += 256) atomicAdd(&cnt[cl[i] >> 8], 1);
  __syncthreads();
  sc[t] = cnt[t];
  __syncthreads();
  for (int off = 1; off < 256; off <<= 1) {
    int v = (t >= off) ? sc[t - off] : 0;
    __syncthreads();
    sc[t] += v;
    __syncthreads();
  }
  lofs[t] = (t == 0) ? 0 : sc[t - 1];
  if (t < NBIN) baseT[t] = blockCnt[(size_t)(r * 2 + 0) * SCAN_L + t * NBLK + blk];
  __syncthreads();
  for (int i = t; i < n; i += 256) {
    int c = cl[i];
    int bin = c >> 8;
    int rank = atomicAdd(&cnt2[bin], 1);
    int p = lofs[bin] + rank;
    pr[p] = ((unsigned)(c & 255) << 16) | (unsigned)rw[i];
    binb[p] = (u8)bin;
  }
  __syncthreads();
  {
    unsigned* pd = pairD + (size_t)r * NE;
    for (int i = t; i < n; i += 256) {
      int bin = binb[i];
      pd[baseT[bin] + (i - lofs[bin])] = pr[i];
    }
  }
  __syncthreads();

  // ---------- src side ----------
  cnt[t] = 0; cnt2[t] = 0;
  __syncthreads();
  for (int i = t; i < n; i += 256) atomicAdd(&cnt[rw[i] >> 8], 1);
  __syncthreads();
  sc[t] = cnt[t];
  __syncthreads();
  for (int off = 1; off < 256; off <<= 1) {
    int v = (t >= off) ? sc[t - off] : 0;
    __syncthreads();
    sc[t] += v;
    __syncthreads();
  }
  lofs[t] = (t == 0) ? 0 : sc[t - 1];
  if (t < NBIN) baseT[t] = blockCnt[(size_t)(r * 2 + 1) * SCAN_L + t * NBLK + blk];
  __syncthreads();
  for (int i = t; i < n; i += 256) {
    int sv = rw[i];
    int bin = sv >> 8;
    int rank = atomicAdd(&cnt2[bin], 1);
    int p = lofs[bin] + rank;
    pay8[p] = (u8)(sv & 255);
    binb[p] = (u8)bin;
  }
  __syncthreads();
  {
    u8* sb = srcb + (size_t)r * NE;
    for (int i = t; i < n; i += 256) {
      int bin = binb[i];
      sb[baseT[bin] + (i - lofs[bin])] = pay8[i];
    }
  }
}

// P2: per dst-bucket -> rowptr, dinvD, and node-sorted srcidx (u16)
__global__ __launch_bounds__(256) void p2_csr(const unsigned* __restrict__ pairD,
                                              const int* __restrict__ bucketBase,
                                              u16* __restrict__ srcidx,
                                              int* __restrict__ rowptr,
                                              float* __restrict__ dinvD) {
  const int r = blockIdx.y, bin = blockIdx.x, t = threadIdx.x;
  const int* bb = bucketBase + (r * 2 + 0) * (NBIN + 1);
  const int base = bb[bin], next = bb[bin + 1];
  const int span = next - base;
  const unsigned* pd = pairD + (size_t)r * NE + base;

  __shared__ int cnt[256], sc[256], ex[256], cnt2[256];
  __shared__ u16 lsrc[CAP2];
  cnt[t] = 0; cnt2[t] = 0;
  __syncthreads();
  for (int i = t; i < span; i += 256) atomicAdd(&cnt[pd[i] >> 16], 1);
  __syncthreads();
  sc[t] = cnt[t];
  __syncthreads();
  for (int off = 1; off < 256; off <<= 1) {
    int v = (t >= off) ? sc[t - off] : 0;
    __syncthreads();
    sc[t] += v;
    __syncthreads();
  }
  ex[t] = (t == 0) ? 0 : sc[t - 1];
  __syncthreads();

  const int node = (bin << 8) + t;
  if (node < NV) {
    rowptr[r * (NV + 1) + node] = base + ex[t];
    float deg = (float)cnt[t];
    dinvD[r * NV + node] = (r < 2) ? rsqrtf(deg + 1.f)
                                   : (deg > 0.f ? rsqrtf(deg) : 0.f);
  }
  if (bin == NBIN - 1 && t == 0) rowptr[r * (NV + 1) + NV] = NE;

  u16* so = srcidx + (size_t)r * NE + base;
  if (span <= CAP2) {
    for (int i = t; i < span; i += 256) {
      unsigned v = pd[i];
      int dl = v >> 16;
      int rank = atomicAdd(&cnt2[dl], 1);
      lsrc[ex[dl] + rank] = (u16)(v & 0xFFFFu);
    }
    __syncthreads();
    for (int i = t; i < span; i += 256) so[i] = lsrc[i];
  } else {  // practically unreachable fallback
    for (int i = t; i < span; i += 256) {
      unsigned v = pd[i];
      int dl = v >> 16;
      int rank = atomicAdd(&cnt2[dl], 1);
      so[ex[dl] + rank] = (u16)(v & 0xFFFFu);
    }
  }
}

// P2': per src-bucket -> dinvS
__global__ __launch_bounds__(256) void p2_srcdeg(const u8* __restrict__ srcb,
                                                 const int* __restrict__ bucketBase,
                                                 float* __restrict__ dinvS) {
  const int r = blockIdx.y, bin = blockIdx.x, t = threadIdx.x;
  const int* bb = bucketBase + (r * 2 + 1) * (NBIN + 1);
  const int base = bb[bin], next = bb[bin + 1];
  const int span = next - base;
  const u8* sb = srcb + (size_t)r * NE + base;
  __shared__ int cnt[256];
  cnt[t] = 0;
  __syncthreads();
  for (int i = t; i < span; i += 256) atomicAdd(&cnt[sb[i]], 1);
  __syncthreads();
  int node = (bin << 8) + t;
  if (node < NV) {
    float deg = (float)cnt[t];
    dinvS[r * NV + node] = (r < 2) ? rsqrtf(deg + 1.f)
                                   : (deg > 0.f ? rsqrtf(deg) : 0.f);
  }
}

// ================= dual GEMM: H[r,:] = bf16( dS[r] * (X[r,:] @ W) ) =================
__global__ __launch_bounds__(256) void gemm_dual(
    const float* __restrict__ X0, const float* __restrict__ W0,
    const float* __restrict__ dS0, bf16_t* __restrict__ H0,
    const float* __restrict__ X1, const float* __restrict__ W1,
    const float* __restrict__ dS1, bf16_t* __restrict__ H1) {
  const float* X; const float* W; const float* dS; bf16_t* H;
  if (blockIdx.y == 0) { X = X0; W = W0; dS = dS0; H = H0; }
  else                 { X = X1; W = W1; dS = dS1; H = H1; }

  __shared__ float Xs[128][33];
  __shared__ float Wk[32][132];
  const int tid = threadIdx.x;
  const int row0 = blockIdx.x * 128;
  const int tx = tid & 15, ty = tid >> 4;

  float acc[8][8] = {};

  for (int kc = 0; kc < FD; kc += 32) {
    __syncthreads();
    #pragma unroll
    for (int j = 0; j < 4; ++j) {
      int idx = tid + j * 256;
      int r = idx >> 3, c = (idx & 7) * 4;
      float4 v = make_float4(0.f, 0.f, 0.f, 0.f);
      int gr = row0 + r;
      if (gr < NV) v = *(const float4*)(X + (size_t)gr * FD + kc + c);
      Xs[r][c + 0] = v.x; Xs[r][c + 1] = v.y; Xs[r][c + 2] = v.z; Xs[r][c + 3] = v.w;
    }
    #pragma unroll
    for (int j = 0; j < 4; ++j) {
      int idx = tid + j * 256;
      int r = idx >> 5, c = (idx & 31) * 4;
      float4 v = *(const float4*)(W + (size_t)(kc + r) * FD + c);
      *(float4*)&Wk[r][c] = v;
    }
    __syncthreads();

    #pragma unroll
    for (int k = 0; k < 32; ++k) {
      float xv[8];
      #pragma unroll
      for (int i = 0; i < 8; ++i) xv[i] = Xs[ty * 8 + i][k];
      float4 wa = *(const float4*)&Wk[k][tx * 4];
      float4 wb = *(const float4*)&Wk[k][64 + tx * 4];
      #pragma unroll
      for (int i = 0; i < 8; ++i) {
        acc[i][0] = fmaf(xv[i], wa.x, acc[i][0]);
        acc[i][1] = fmaf(xv[i], wa.y, acc[i][1]);
        acc[i][2] = fmaf(xv[i], wa.z, acc[i][2]);
        acc[i][3] = fmaf(xv[i], wa.w, acc[i][3]);
        acc[i][4] = fmaf(xv[i], wb.x, acc[i][4]);
        acc[i][5] = fmaf(xv[i], wb.y, acc[i][5]);
        acc[i][6] = fmaf(xv[i], wb.z, acc[i][6]);
        acc[i][7] = fmaf(xv[i], wb.w, acc[i][7]);
      }
    }
  }

  #pragma unroll
  for (int i = 0; i < 8; ++i) {
    int r = row0 + ty * 8 + i;
    if (r < NV) {
      float s = dS[r];
      unsigned a0 = (unsigned)f2bf(acc[i][0] * s) | ((unsigned)f2bf(acc[i][1] * s) << 16);
      unsigned a1 = (unsigned)f2bf(acc[i][2] * s) | ((unsigned)f2bf(acc[i][3] * s) << 16);
      unsigned b0 = (unsigned)f2bf(acc[i][4] * s) | ((unsigned)f2bf(acc[i][5] * s) << 16);
      unsigned b1 = (unsigned)f2bf(acc[i][6] * s) | ((unsigned)f2bf(acc[i][7] * s) << 16);
      *(uint2*)(H + (size_t)r * FD + tx * 4)      = make_uint2(a0, a1);
      *(uint2*)(H + (size_t)r * FD + 64 + tx * 4) = make_uint2(b0, b1);
    }
  }
}

// ================= fused pull aggregation =================
__device__ __forceinline__ void gather_acc(const bf16_t* __restrict__ h,
                                           const u16* __restrict__ src,
                                           int p0, int p1, int d,
                                           float& ax, float& ay) {
  int p = p0;
  for (; p + 4 <= p1; p += 4) {
    int s0 = src[p], s1 = src[p + 1], s2 = src[p + 2], s3 = src[p + 3];
    unsigned v0 = *(const unsigned*)(h + ((size_t)s0 << 7) + d);
    unsigned v1 = *(const unsigned*)(h + ((size_t)s1 << 7) + d);
    unsigned v2 = *(const unsigned*)(h + ((size_t)s2 << 7) + d);
    unsigned v3 = *(const unsigned*)(h + ((size_t)s3 << 7) + d);
    ax += bflo(v0); ay += bfhi(v0);
    ax += bflo(v1); ay += bfhi(v1);
    ax += bflo(v2); ay += bfhi(v2);
    ax += bflo(v3); ay += bfhi(v3);
  }
  for (; p < p1; ++p) {
    int s = src[p];
    unsigned v = *(const unsigned*)(h + ((size_t)s << 7) + d);
    ax += bflo(v); ay += bfhi(v);
  }
}

__global__ __launch_bounds__(256) void pull2(
    const bf16_t* __restrict__ hA, const int* __restrict__ rpA, const u16* __restrict__ srcA,
    const float* __restrict__ dDA,
    const bf16_t* __restrict__ hB, const int* __restrict__ rpB, const u16* __restrict__ srcB,
    const float* __restrict__ dDB,
    const float* __restrict__ bA, const float* __restrict__ bB,
    float* __restrict__ Y) {
  const int i = (blockIdx.x * 256 + threadIdx.x) >> 6;
  const int lane = threadIdx.x & 63;
  if (i >= NV) return;
  const int d = lane * 2;

  float ax, ay;
  {
    unsigned v = *(const unsigned*)(hA + ((size_t)i << 7) + d);
    ax = bflo(v); ay = bfhi(v);
  }
  gather_acc(hA, srcA, rpA[i], rpA[i + 1], d, ax, ay);
  float bx = 0.f, by = 0.f;
  gather_acc(hB, srcB, rpB[i], rpB[i + 1], d, bx, by);

  float wA = dDA[i], wB = dDB[i];
  float ox = fmaf(ax, wA, fmaf(bx, wB, bA[d] + bB[d]));
  float oy = fmaf(ay, wA, fmaf(by, wB, bA[d + 1] + bB[d + 1]));
  *(float2*)(Y + (size_t)i * FD + d) = make_float2(fmaxf(ox, 0.f), fmaxf(oy, 0.f));
}

// ================= final linear =================
__global__ __launch_bounds__(256) void linear64(const float* __restrict__ X,
                                                const float* __restrict__ lw,
                                                const float* __restrict__ lb,
                                                float* __restrict__ Out) {
  __shared__ float Wt[128][68];
  __shared__ float Xs[64][132];
  const int tid = threadIdx.x;
  const int row0 = blockIdx.x * 64;

  for (int i = tid * 4; i < 64 * 128; i += 1024) {
    float4 v = *(const float4*)(lw + i);
    int o = i >> 7, h = i & 127;
    Wt[h + 0][o] = v.x; Wt[h + 1][o] = v.y; Wt[h + 2][o] = v.z; Wt[h + 3][o] = v.w;
  }
  for (int i = tid * 4; i < 64 * 128; i += 1024) {
    int rr = i >> 7, cc = i & 127;
    int gr = row0 + rr;
    float4 v = make_float4(0.f, 0.f, 0.f, 0.f);
    if (gr < NV) v = *(const float4*)(X + (size_t)gr * FD + cc);
    *(float4*)&Xs[rr][cc] = v;
  }
  __syncthreads();

  const int tx = tid & 15, ty = tid >> 4;
  float acc[4][4];
  #pragma unroll
  for (int i = 0; i < 4; ++i)
    #pragma unroll
    for (int j = 0; j < 4; ++j) acc[i][j] = 0.f;

  for (int k = 0; k < 128; k += 4) {
    float4 xr[4], w[4];
    #pragma unroll
    for (int i = 0; i < 4; ++i) xr[i] = *(const float4*)&Xs[ty * 4 + i][k];
    #pragma unroll
    for (int j = 0; j < 4; ++j) w[j] = *(const float4*)&Wt[k + j][tx * 4];
    #pragma unroll
    for (int i = 0; i < 4; ++i) {
      const float* xv = (const float*)&xr[i];
      #pragma unroll
      for (int j = 0; j < 4; ++j) {
        float x = xv[j];
        acc[i][0] = fmaf(x, w[j].x, acc[i][0]);
        acc[i][1] = fmaf(x, w[j].y, acc[i][1]);
        acc[i][2] = fmaf(x, w[j].z, acc[i][2]);
        acc[i][3] = fmaf(x, w[j].w, acc[i][3]);
      }
    }
  }
  float4 bias = *(const float4*)(lb + tx * 4);
  #pragma unroll
  for (int i = 0; i < 4; ++i) {
    int gr = row0 + ty * 4 + i;
    if (gr < NV) {
      *(float4*)(Out + (size_t)gr * NOUT + tx * 4) =
          make_float4(acc[i][0] + bias.x, acc[i][1] + bias.y,
                      acc[i][2] + bias.z, acc[i][3] + bias.w);
    }
  }
}

// ================= host orchestration =================

extern "C" void kernel_launch(void* const* d_in, const int* in_sizes, int n_in,
                              void* d_out, int out_size, void* d_ws, size_t ws_size,
                              hipStream_t stream) {
  const float* x_drug = (const float*)d_in[0];
  const float* x_dis  = (const float*)d_in[1];
  const int* ei[4] = { (const int*)d_in[2], (const int*)d_in[3],
                       (const int*)d_in[4], (const int*)d_in[5] };  // dd, ss, ds, sd
  const float* Ws = (const float*)d_in[6];
  const float* bs = (const float*)d_in[7];
  const float* lw = (const float*)d_in[8];
  const float* lb = (const float*)d_in[9];
  float* out = (float*)d_out;

  char* p = (char*)d_ws;
  auto take = [&](size_t bytes) -> void* {
    char* q = p;
    p += (bytes + 255) & ~(size_t)255;
    return (void*)q;
  };
  int* blockCnt   = (int*)take((size_t)8 * SCAN_L * sizeof(int));       // 2.45MB
  int* bucketBase = (int*)take((size_t)8 * (NBIN + 1) * sizeof(int));
  unsigned* pairD = (unsigned*)take((size_t)4 * NE * sizeof(unsigned)); // 12.8MB
  u8* srcb        = (u8*)take((size_t)4 * NE);                          // 3.2MB
  u16* srcidx     = (u16*)take((size_t)4 * NE * sizeof(u16));           // 6.4MB
  int* rowptr     = (int*)take((size_t)4 * (NV + 1) * sizeof(int));
  float* dinvS    = (float*)take((size_t)4 * NV * sizeof(float));
  float* dinvD    = (float*)take((size_t)4 * NV * sizeof(float));
  bf16_t* hA = (bf16_t*)take((size_t)NV * FD * sizeof(bf16_t));
  bf16_t* hB = (bf16_t*)take((size_t)NV * FD * sizeof(bf16_t));
  float* XD1 = (float*)take((size_t)NV * FD * sizeof(float));
  float* XS1 = (float*)take((size_t)NV * FD * sizeof(float));
  float* XD2 = (float*)take((size_t)NV * FD * sizeof(float));
  float* XS2 = (float*)take((size_t)NV * FD * sizeof(float));

  Ptr4 rows = {{ ei[0], ei[1], ei[2], ei[3] }};
  Ptr4 cols = {{ ei[0] + NE, ei[1] + NE, ei[2] + NE, ei[3] + NE }};

  // ---- prep: bucket-sorted CSR + degree norms, zero global atomics ----
  p0_hist<<<dim3(NBLK, 4), 256, 0, stream>>>(rows, cols, blockCnt);
  p_scan<<<8, 1024, 0, stream>>>(blockCnt, bucketBase);
  p1_scatter<<<dim3(NBLK, 4), 256, 0, stream>>>(rows, cols, blockCnt, pairD, srcb);
  p2_csr<<<dim3(NBIN, 4), 256, 0, stream>>>(pairD, bucketBase, srcidx, rowptr, dinvD);
  p2_srcdeg<<<dim3(NBIN, 4), 256, 0, stream>>>(srcb, bucketBase, dinvS);

  // ---- layers ----
  const dim3 GEMM_GRID((NV + 127) / 128, 2);
  const int PULL_GRID = NV * 64 / 256;
  const int LIN_GRID = (NV + 63) / 64;
  const float* xd = x_drug;
  const float* xs = x_dis;
  float* nextd[2] = {XD1, XD2};
  float* nexts[2] = {XS1, XS2};
  for (int l = 0; l < 2; ++l) {
    const float* W0 = Ws + (size_t)(l * 4 + 0) * FD * FD;
    const float* W1 = Ws + (size_t)(l * 4 + 1) * FD * FD;
    const float* W2 = Ws + (size_t)(l * 4 + 2) * FD * FD;
    const float* W3 = Ws + (size_t)(l * 4 + 3) * FD * FD;
    const float* b0 = bs + (l * 4 + 0) * FD;
    const float* b1 = bs + (l * 4 + 1) * FD;
    const float* b2 = bs + (l * 4 + 2) * FD;
    const float* b3 = bs + (l * 4 + 3) * FD;

    gemm_dual<<<GEMM_GRID, 256, 0, stream>>>(xd, W0, dinvS + 0 * NV, hA,
                                             xs, W3, dinvS + 3 * NV, hB);
    pull2<<<PULL_GRID, 256, 0, stream>>>(
        hA, rowptr + 0 * (NV + 1), srcidx + (size_t)0 * NE, dinvD + 0 * NV,
        hB, rowptr + 3 * (NV + 1), srcidx + (size_t)3 * NE, dinvD + 3 * NV,
        b0, b3, nextd[l]);

    gemm_dual<<<GEMM_GRID, 256, 0, stream>>>(xs, W1, dinvS + 1 * NV, hA,
                                             xd, W2, dinvS + 2 * NV, hB);
    pull2<<<PULL_GRID, 256, 0, stream>>>(
        hA, rowptr + 1 * (NV + 1), srcidx + (size_t)1 * NE, dinvD + 1 * NV,
        hB, rowptr + 2 * (NV + 1), srcidx + (size_t)2 * NE, dinvD + 2 * NV,
        b1, b2, nexts[l]);

    xd = nextd[l];
    xs = nexts[l];
  }

  linear64<<<LIN_GRID, 256, 0, stream>>>(xd, lw, lb, out);
  linear64<<<LIN_GRID, 256, 0, stream>>>(xs, lw, lb, out + (size_t)NV * NOUT);
}

// Round 4
// 652.251 us; speedup vs baseline: 2.6394x; 1.2180x over previous
//
#include <hip/hip_runtime.h>

#define NV   50000
#define FD   128
#define NE   800000
#define NOUT 64
#define NBIN 196          // ceil(NV/256) coarse buckets of 256 nodes
#define CH   2048         // edges per block in P0/P1
#define NBLK 391          // ceil(NE/CH)
#define SCAN_L (NBIN * NBLK)
#define SCHUNK 2048       // elements per block in hierarchical scan
#define NSCH ((SCAN_L + SCHUNK - 1) / SCHUNK)   // 38
#define CAP2 12288        // LDS staging cap in P2 (avg span ~4083)

typedef unsigned short bf16_t;
typedef unsigned short u16;
typedef unsigned char  u8;

__device__ __forceinline__ bf16_t f2bf(float f) {
  unsigned u = __builtin_bit_cast(unsigned, f);
  return (bf16_t)((u + 0x7fffu + ((u >> 16) & 1u)) >> 16);
}
__device__ __forceinline__ float bflo(unsigned v) { return __builtin_bit_cast(float, v << 16); }
__device__ __forceinline__ float bfhi(unsigned v) { return __builtin_bit_cast(float, v & 0xffff0000u); }

struct Ptr4 { const int* p[4]; };

// ================= bucket-sort based CSR build (no global atomics) =================

// P0: per-(block,bin) histograms of dst and src, via LDS atomics
__global__ __launch_bounds__(256) void p0_hist(Ptr4 rows, Ptr4 cols,
                                               int* __restrict__ blockCnt) {
  const int r = blockIdx.y, blk = blockIdx.x, t = threadIdx.x;
  __shared__ int cd[NBIN], cs[NBIN];
  for (int i = t; i < NBIN; i += 256) { cd[i] = 0; cs[i] = 0; }
  __syncthreads();
  const int e0 = blk * CH;
  const int n = min(CH, NE - e0);
  const int* rw = rows.p[r] + e0;
  const int* cl = cols.p[r] + e0;
  for (int i = t; i < n; i += 256) {
    atomicAdd(&cd[cl[i] >> 8], 1);
    atomicAdd(&cs[rw[i] >> 8], 1);
  }
  __syncthreads();
  int* bd = blockCnt + (size_t)(r * 2 + 0) * SCAN_L;
  int* bs = blockCnt + (size_t)(r * 2 + 1) * SCAN_L;
  for (int i = t; i < NBIN; i += 256) {
    bd[i * NBLK + blk] = cd[i];
    bs[i * NBLK + blk] = cs[i];
  }
}

// ---- hierarchical exclusive scan over each of 8 windows of SCAN_L ints ----

// pass1: per-chunk sums
__global__ __launch_bounds__(256) void scan_pass1(const int* __restrict__ blockCnt,
                                                  int* __restrict__ chunkSum) {
  const int r2 = blockIdx.y, chunk = blockIdx.x, t = threadIdx.x;
  const int* a = blockCnt + (size_t)r2 * SCAN_L + chunk * SCHUNK;
  const int n = min(SCHUNK, SCAN_L - chunk * SCHUNK);
  int s = 0;
  for (int i = t; i < n; i += 256) s += a[i];
  __shared__ int sm[256];
  sm[t] = s;
  __syncthreads();
  #pragma unroll
  for (int off = 128; off > 0; off >>= 1) {
    if (t < off) sm[t] += sm[t + off];
    __syncthreads();
  }
  if (t == 0) chunkSum[r2 * NSCH + chunk] = sm[0];
}

// pass2: one block turns chunk sums into exclusive chunk bases (per window)
__global__ __launch_bounds__(512) void scan_pass2(int* __restrict__ chunkSum,
                                                  int* __restrict__ bucketBase) {
  const int t = threadIdx.x;
  __shared__ int sm[8 * NSCH];
  if (t < 8 * NSCH) sm[t] = chunkSum[t];
  __syncthreads();
  if (t < 8) {
    int run = 0;
    for (int j = 0; j < NSCH; ++j) {
      int v = sm[t * NSCH + j];
      sm[t * NSCH + j] = run;
      run += v;
    }
    bucketBase[t * (NBIN + 1) + NBIN] = NE;
  }
  __syncthreads();
  if (t < 8 * NSCH) chunkSum[t] = sm[t];
}

// pass3: block-local exclusive scan + chunk base; emit bucketBase at bin starts
__global__ __launch_bounds__(256) void scan_pass3(int* __restrict__ blockCnt,
                                                  const int* __restrict__ chunkSum,
                                                  int* __restrict__ bucketBase) {
  const int r2 = blockIdx.y, chunk = blockIdx.x, t = threadIdx.x;
  int* a = blockCnt + (size_t)r2 * SCAN_L + chunk * SCHUNK;
  const int gbase = chunk * SCHUNK;
  const int n = min(SCHUNK, SCAN_L - gbase);
  const int idx0 = t * 8;
  int v[8];
  int s = 0;
  #pragma unroll
  for (int j = 0; j < 8; ++j) {
    int id = idx0 + j;
    v[j] = (id < n) ? a[id] : 0;
    s += v[j];
  }
  __shared__ int sm[256];
  sm[t] = s;
  __syncthreads();
  for (int off = 1; off < 256; off <<= 1) {
    int x = (t >= off) ? sm[t - off] : 0;
    __syncthreads();
    sm[t] += x;
    __syncthreads();
  }
  int pre = ((t == 0) ? 0 : sm[t - 1]) + chunkSum[r2 * NSCH + chunk];
  #pragma unroll
  for (int j = 0; j < 8; ++j) {
    int id = idx0 + j;
    if (id < n) {
      int val = v[j];
      a[id] = pre;
      int g = gbase + id;
      if (g % NBLK == 0) bucketBase[r2 * (NBIN + 1) + g / NBLK] = pre;
      pre += val;
    }
  }
}

// P1: scatter edges into dst-buckets (packed pairs) and src-buckets (u8 locals),
// LDS-reordered for coalesced output; positions fully precomputed (deterministic)
__global__ __launch_bounds__(256) void p1_scatter(Ptr4 rows, Ptr4 cols,
                                                  const int* __restrict__ blockCnt,
                                                  unsigned* __restrict__ pairD,
                                                  u8* __restrict__ srcb) {
  const int r = blockIdx.y, blk = blockIdx.x, t = threadIdx.x;
  const int e0 = blk * CH;
  const int n = min(CH, NE - e0);
  const int* rw = rows.p[r] + e0;
  const int* cl = cols.p[r] + e0;

  __shared__ int cnt[256], sc[256], lofs[256], cnt2[256], baseT[256];
  __shared__ unsigned pr[CH];
  __shared__ u8 binb[CH];
  __shared__ u8 pay8[CH];

  // ---------- dst side ----------
  cnt[t] = 0; cnt2[t] = 0;
  __syncthreads();
  for (int i = t; i < n; i += 256) atomicAdd(&cnt[cl[i] >> 8], 1);
  __syncthreads();
  sc[t] = cnt[t];
  __syncthreads();
  for (int off = 1; off < 256; off <<= 1) {
    int v = (t >= off) ? sc[t - off] : 0;
    __syncthreads();
    sc[t] += v;
    __syncthreads();
  }
  lofs[t] = (t == 0) ? 0 : sc[t - 1];
  if (t < NBIN) baseT[t] = blockCnt[(size_t)(r * 2 + 0) * SCAN_L + t * NBLK + blk];
  __syncthreads();
  for (int i = t; i < n; i += 256) {
    int c = cl[i];
    int bin = c >> 8;
    int rank = atomicAdd(&cnt2[bin], 1);
    int p = lofs[bin] + rank;
    pr[p] = ((unsigned)(c & 255) << 16) | (unsigned)rw[i];
    binb[p] = (u8)bin;
  }
  __syncthreads();
  {
    unsigned* pd = pairD + (size_t)r * NE;
    for (int i = t; i < n; i += 256) {
      int bin = binb[i];
      pd[baseT[bin] + (i - lofs[bin])] = pr[i];
    }
  }
  __syncthreads();

  // ---------- src side ----------
  cnt[t] = 0; cnt2[t] = 0;
  __syncthreads();
  for (int i = t; i < n; i += 256) atomicAdd(&cnt[rw[i] >> 8], 1);
  __syncthreads();
  sc[t] = cnt[t];
  __syncthreads();
  for (int off = 1; off < 256; off <<= 1) {
    int v = (t >= off) ? sc[t - off] : 0;
    __syncthreads();
    sc[t] += v;
    __syncthreads();
  }
  lofs[t] = (t == 0) ? 0 : sc[t - 1];
  if (t < NBIN) baseT[t] = blockCnt[(size_t)(r * 2 + 1) * SCAN_L + t * NBLK + blk];
  __syncthreads();
  for (int i = t; i < n; i += 256) {
    int sv = rw[i];
    int bin = sv >> 8;
    int rank = atomicAdd(&cnt2[bin], 1);
    int p = lofs[bin] + rank;
    pay8[p] = (u8)(sv & 255);
    binb[p] = (u8)bin;
  }
  __syncthreads();
  {
    u8* sb = srcb + (size_t)r * NE;
    for (int i = t; i < n; i += 256) {
      int bin = binb[i];
      sb[baseT[bin] + (i - lofs[bin])] = pay8[i];
    }
  }
}

// P2: per dst-bucket -> rowptr, dinvD, and node-sorted srcidx (u16)
__global__ __launch_bounds__(256) void p2_csr(const unsigned* __restrict__ pairD,
                                              const int* __restrict__ bucketBase,
                                              u16* __restrict__ srcidx,
                                              int* __restrict__ rowptr,
                                              float* __restrict__ dinvD) {
  const int r = blockIdx.y, bin = blockIdx.x, t = threadIdx.x;
  const int* bb = bucketBase + (r * 2 + 0) * (NBIN + 1);
  const int base = bb[bin], next = bb[bin + 1];
  const int span = next - base;
  const unsigned* pd = pairD + (size_t)r * NE + base;

  __shared__ int cnt[256], sc[256], ex[256], cnt2[256];
  __shared__ u16 lsrc[CAP2];
  cnt[t] = 0; cnt2[t] = 0;
  __syncthreads();
  for (int i = t; i < span; i += 256) atomicAdd(&cnt[pd[i] >> 16], 1);
  __syncthreads();
  sc[t] = cnt[t];
  __syncthreads();
  for (int off = 1; off < 256; off <<= 1) {
    int v = (t >= off) ? sc[t - off] : 0;
    __syncthreads();
    sc[t] += v;
    __syncthreads();
  }
  ex[t] = (t == 0) ? 0 : sc[t - 1];
  __syncthreads();

  const int node = (bin << 8) + t;
  if (node < NV) {
    rowptr[r * (NV + 1) + node] = base + ex[t];
    float deg = (float)cnt[t];
    dinvD[r * NV + node] = (r < 2) ? rsqrtf(deg + 1.f)
                                   : (deg > 0.f ? rsqrtf(deg) : 0.f);
  }
  if (bin == NBIN - 1 && t == 0) rowptr[r * (NV + 1) + NV] = NE;

  u16* so = srcidx + (size_t)r * NE + base;
  if (span <= CAP2) {
    for (int i = t; i < span; i += 256) {
      unsigned v = pd[i];
      int dl = v >> 16;
      int rank = atomicAdd(&cnt2[dl], 1);
      lsrc[ex[dl] + rank] = (u16)(v & 0xFFFFu);
    }
    __syncthreads();
    for (int i = t; i < span; i += 256) so[i] = lsrc[i];
  } else {  // practically unreachable fallback
    for (int i = t; i < span; i += 256) {
      unsigned v = pd[i];
      int dl = v >> 16;
      int rank = atomicAdd(&cnt2[dl], 1);
      so[ex[dl] + rank] = (u16)(v & 0xFFFFu);
    }
  }
}

// P2': per src-bucket -> dinvS
__global__ __launch_bounds__(256) void p2_srcdeg(const u8* __restrict__ srcb,
                                                 const int* __restrict__ bucketBase,
                                                 float* __restrict__ dinvS) {
  const int r = blockIdx.y, bin = blockIdx.x, t = threadIdx.x;
  const int* bb = bucketBase + (r * 2 + 1) * (NBIN + 1);
  const int base = bb[bin], next = bb[bin + 1];
  const int span = next - base;
  const u8* sb = srcb + (size_t)r * NE + base;
  __shared__ int cnt[256];
  cnt[t] = 0;
  __syncthreads();
  for (int i = t; i < span; i += 256) atomicAdd(&cnt[sb[i]], 1);
  __syncthreads();
  int node = (bin << 8) + t;
  if (node < NV) {
    float deg = (float)cnt[t];
    dinvS[r * NV + node] = (r < 2) ? rsqrtf(deg + 1.f)
                                   : (deg > 0.f ? rsqrtf(deg) : 0.f);
  }
}

// ================= dual GEMM: H[r,:] = bf16( dS[r] * (X[r,:] @ W) ) =================
__global__ __launch_bounds__(256) void gemm_dual(
    const float* __restrict__ X0, const float* __restrict__ W0,
    const float* __restrict__ dS0, bf16_t* __restrict__ H0,
    const float* __restrict__ X1, const float* __restrict__ W1,
    const float* __restrict__ dS1, bf16_t* __restrict__ H1) {
  const float* X; const float* W; const float* dS; bf16_t* H;
  if (blockIdx.y == 0) { X = X0; W = W0; dS = dS0; H = H0; }
  else                 { X = X1; W = W1; dS = dS1; H = H1; }

  __shared__ float Xs[128][33];
  __shared__ float Wk[32][132];
  const int tid = threadIdx.x;
  const int row0 = blockIdx.x * 128;
  const int tx = tid & 15, ty = tid >> 4;

  float acc[8][8] = {};

  for (int kc = 0; kc < FD; kc += 32) {
    __syncthreads();
    #pragma unroll
    for (int j = 0; j < 4; ++j) {
      int idx = tid + j * 256;
      int r = idx >> 3, c = (idx & 7) * 4;
      float4 v = make_float4(0.f, 0.f, 0.f, 0.f);
      int gr = row0 + r;
      if (gr < NV) v = *(const float4*)(X + (size_t)gr * FD + kc + c);
      Xs[r][c + 0] = v.x; Xs[r][c + 1] = v.y; Xs[r][c + 2] = v.z; Xs[r][c + 3] = v.w;
    }
    #pragma unroll
    for (int j = 0; j < 4; ++j) {
      int idx = tid + j * 256;
      int r = idx >> 5, c = (idx & 31) * 4;
      float4 v = *(const float4*)(W + (size_t)(kc + r) * FD + c);
      *(float4*)&Wk[r][c] = v;
    }
    __syncthreads();

    #pragma unroll
    for (int k = 0; k < 32; ++k) {
      float xv[8];
      #pragma unroll
      for (int i = 0; i < 8; ++i) xv[i] = Xs[ty * 8 + i][k];
      float4 wa = *(const float4*)&Wk[k][tx * 4];
      float4 wb = *(const float4*)&Wk[k][64 + tx * 4];
      #pragma unroll
      for (int i = 0; i < 8; ++i) {
        acc[i][0] = fmaf(xv[i], wa.x, acc[i][0]);
        acc[i][1] = fmaf(xv[i], wa.y, acc[i][1]);
        acc[i][2] = fmaf(xv[i], wa.z, acc[i][2]);
        acc[i][3] = fmaf(xv[i], wa.w, acc[i][3]);
        acc[i][4] = fmaf(xv[i], wb.x, acc[i][4]);
        acc[i][5] = fmaf(xv[i], wb.y, acc[i][5]);
        acc[i][6] = fmaf(xv[i], wb.z, acc[i][6]);
        acc[i][7] = fmaf(xv[i], wb.w, acc[i][7]);
      }
    }
  }

  #pragma unroll
  for (int i = 0; i < 8; ++i) {
    int r = row0 + ty * 8 + i;
    if (r < NV) {
      float s = dS[r];
      unsigned a0 = (unsigned)f2bf(acc[i][0] * s) | ((unsigned)f2bf(acc[i][1] * s) << 16);
      unsigned a1 = (unsigned)f2bf(acc[i][2] * s) | ((unsigned)f2bf(acc[i][3] * s) << 16);
      unsigned b0 = (unsigned)f2bf(acc[i][4] * s) | ((unsigned)f2bf(acc[i][5] * s) << 16);
      unsigned b1 = (unsigned)f2bf(acc[i][6] * s) | ((unsigned)f2bf(acc[i][7] * s) << 16);
      *(uint2*)(H + (size_t)r * FD + tx * 4)      = make_uint2(a0, a1);
      *(uint2*)(H + (size_t)r * FD + 64 + tx * 4) = make_uint2(b0, b1);
    }
  }
}

// ================= fused pull aggregation =================
__device__ __forceinline__ void gather_acc(const bf16_t* __restrict__ h,
                                           const u16* __restrict__ src,
                                           int p0, int p1, int d,
                                           float& ax, float& ay) {
  int p = p0;
  for (; p + 4 <= p1; p += 4) {
    int s0 = src[p], s1 = src[p + 1], s2 = src[p + 2], s3 = src[p + 3];
    unsigned v0 = *(const unsigned*)(h + ((size_t)s0 << 7) + d);
    unsigned v1 = *(const unsigned*)(h + ((size_t)s1 << 7) + d);
    unsigned v2 = *(const unsigned*)(h + ((size_t)s2 << 7) + d);
    unsigned v3 = *(const unsigned*)(h + ((size_t)s3 << 7) + d);
    ax += bflo(v0); ay += bfhi(v0);
    ax += bflo(v1); ay += bfhi(v1);
    ax += bflo(v2); ay += bfhi(v2);
    ax += bflo(v3); ay += bfhi(v3);
  }
  for (; p < p1; ++p) {
    int s = src[p];
    unsigned v = *(const unsigned*)(h + ((size_t)s << 7) + d);
    ax += bflo(v); ay += bfhi(v);
  }
}

__global__ __launch_bounds__(256) void pull2(
    const bf16_t* __restrict__ hA, const int* __restrict__ rpA, const u16* __restrict__ srcA,
    const float* __restrict__ dDA,
    const bf16_t* __restrict__ hB, const int* __restrict__ rpB, const u16* __restrict__ srcB,
    const float* __restrict__ dDB,
    const float* __restrict__ bA, const float* __restrict__ bB,
    float* __restrict__ Y) {
  const int i = (blockIdx.x * 256 + threadIdx.x) >> 6;
  const int lane = threadIdx.x & 63;
  if (i >= NV) return;
  const int d = lane * 2;

  float ax, ay;
  {
    unsigned v = *(const unsigned*)(hA + ((size_t)i << 7) + d);
    ax = bflo(v); ay = bfhi(v);
  }
  gather_acc(hA, srcA, rpA[i], rpA[i + 1], d, ax, ay);
  float bx = 0.f, by = 0.f;
  gather_acc(hB, srcB, rpB[i], rpB[i + 1], d, bx, by);

  float wA = dDA[i], wB = dDB[i];
  float ox = fmaf(ax, wA, fmaf(bx, wB, bA[d] + bB[d]));
  float oy = fmaf(ay, wA, fmaf(by, wB, bA[d + 1] + bB[d + 1]));
  *(float2*)(Y + (size_t)i * FD + d) = make_float2(fmaxf(ox, 0.f), fmaxf(oy, 0.f));
}

// ================= final linear =================
__global__ __launch_bounds__(256) void linear64(const float* __restrict__ X,
                                                const float* __restrict__ lw,
                                                const float* __restrict__ lb,
                                                float* __restrict__ Out) {
  __shared__ float Wt[128][68];
  __shared__ float Xs[64][132];
  const int tid = threadIdx.x;
  const int row0 = blockIdx.x * 64;

  for (int i = tid * 4; i < 64 * 128; i += 1024) {
    float4 v = *(const float4*)(lw + i);
    int o = i >> 7, h = i & 127;
    Wt[h + 0][o] = v.x; Wt[h + 1][o] = v.y; Wt[h + 2][o] = v.z; Wt[h + 3][o] = v.w;
  }
  for (int i = tid * 4; i < 64 * 128; i += 1024) {
    int rr = i >> 7, cc = i & 127;
    int gr = row0 + rr;
    float4 v = make_float4(0.f, 0.f, 0.f, 0.f);
    if (gr < NV) v = *(const float4*)(X + (size_t)gr * FD + cc);
    *(float4*)&Xs[rr][cc] = v;
  }
  __syncthreads();

  const int tx = tid & 15, ty = tid >> 4;
  float acc[4][4];
  #pragma unroll
  for (int i = 0; i < 4; ++i)
    #pragma unroll
    for (int j = 0; j < 4; ++j) acc[i][j] = 0.f;

  for (int k = 0; k < 128; k += 4) {
    float4 xr[4], w[4];
    #pragma unroll
    for (int i = 0; i < 4; ++i) xr[i] = *(const float4*)&Xs[ty * 4 + i][k];
    #pragma unroll
    for (int j = 0; j < 4; ++j) w[j] = *(const float4*)&Wt[k + j][tx * 4];
    #pragma unroll
    for (int i = 0; i < 4; ++i) {
      const float* xv = (const float*)&xr[i];
      #pragma unroll
      for (int j = 0; j < 4; ++j) {
        float x = xv[j];
        acc[i][0] = fmaf(x, w[j].x, acc[i][0]);
        acc[i][1] = fmaf(x, w[j].y, acc[i][1]);
        acc[i][2] = fmaf(x, w[j].z, acc[i][2]);
        acc[i][3] = fmaf(x, w[j].w, acc[i][3]);
      }
    }
  }
  float4 bias = *(const float4*)(lb + tx * 4);
  #pragma unroll
  for (int i = 0; i < 4; ++i) {
    int gr = row0 + ty * 4 + i;
    if (gr < NV) {
      *(float4*)(Out + (size_t)gr * NOUT + tx * 4) =
          make_float4(acc[i][0] + bias.x, acc[i][1] + bias.y,
                      acc[i][2] + bias.z, acc[i][3] + bias.w);
    }
  }
}

// ================= host orchestration =================

extern "C" void kernel_launch(void* const* d_in, const int* in_sizes, int n_in,
                              void* d_out, int out_size, void* d_ws, size_t ws_size,
                              hipStream_t stream) {
  const float* x_drug = (const float*)d_in[0];
  const float* x_dis  = (const float*)d_in[1];
  const int* ei[4] = { (const int*)d_in[2], (const int*)d_in[3],
                       (const int*)d_in[4], (const int*)d_in[5] };  // dd, ss, ds, sd
  const float* Ws = (const float*)d_in[6];
  const float* bs = (const float*)d_in[7];
  const float* lw = (const float*)d_in[8];
  const float* lb = (const float*)d_in[9];
  float* out = (float*)d_out;

  char* p = (char*)d_ws;
  auto take = [&](size_t bytes) -> void* {
    char* q = p;
    p += (bytes + 255) & ~(size_t)255;
    return (void*)q;
  };
  int* blockCnt   = (int*)take((size_t)8 * SCAN_L * sizeof(int));       // 2.45MB
  int* chunkSum   = (int*)take((size_t)8 * NSCH * sizeof(int));
  int* bucketBase = (int*)take((size_t)8 * (NBIN + 1) * sizeof(int));
  unsigned* pairD = (unsigned*)take((size_t)4 * NE * sizeof(unsigned)); // 12.8MB
  u8* srcb        = (u8*)take((size_t)4 * NE);                          // 3.2MB
  u16* srcidx     = (u16*)take((size_t)4 * NE * sizeof(u16));           // 6.4MB
  int* rowptr     = (int*)take((size_t)4 * (NV + 1) * sizeof(int));
  float* dinvS    = (float*)take((size_t)4 * NV * sizeof(float));
  float* dinvD    = (float*)take((size_t)4 * NV * sizeof(float));
  bf16_t* hA = (bf16_t*)take((size_t)NV * FD * sizeof(bf16_t));
  bf16_t* hB = (bf16_t*)take((size_t)NV * FD * sizeof(bf16_t));
  float* XD1 = (float*)take((size_t)NV * FD * sizeof(float));
  float* XS1 = (float*)take((size_t)NV * FD * sizeof(float));
  float* XD2 = (float*)take((size_t)NV * FD * sizeof(float));
  float* XS2 = (float*)take((size_t)NV * FD * sizeof(float));

  Ptr4 rows = {{ ei[0], ei[1], ei[2], ei[3] }};
  Ptr4 cols = {{ ei[0] + NE, ei[1] + NE, ei[2] + NE, ei[3] + NE }};

  // ---- prep: bucket-sorted CSR + degree norms, zero global atomics ----
  p0_hist<<<dim3(NBLK, 4), 256, 0, stream>>>(rows, cols, blockCnt);
  scan_pass1<<<dim3(NSCH, 8), 256, 0, stream>>>(blockCnt, chunkSum);
  scan_pass2<<<1, 512, 0, stream>>>(chunkSum, bucketBase);
  scan_pass3<<<dim3(NSCH, 8), 256, 0, stream>>>(blockCnt, chunkSum, bucketBase);
  p1_scatter<<<dim3(NBLK, 4), 256, 0, stream>>>(rows, cols, blockCnt, pairD, srcb);
  p2_csr<<<dim3(NBIN, 4), 256, 0, stream>>>(pairD, bucketBase, srcidx, rowptr, dinvD);
  p2_srcdeg<<<dim3(NBIN, 4), 256, 0, stream>>>(srcb, bucketBase, dinvS);

  // ---- layers ----
  const dim3 GEMM_GRID((NV + 127) / 128, 2);
  const int PULL_GRID = NV * 64 / 256;
  const int LIN_GRID = (NV + 63) / 64;
  const float* xd = x_drug;
  const float* xs = x_dis;
  float* nextd[2] = {XD1, XD2};
  float* nexts[2] = {XS1, XS2};
  for (int l = 0; l < 2; ++l) {
    const float* W0 = Ws + (size_t)(l * 4 + 0) * FD * FD;
    const float* W1 = Ws + (size_t)(l * 4 + 1) * FD * FD;
    const float* W2 = Ws + (size_t)(l * 4 + 2) * FD * FD;
    const float* W3 = Ws + (size_t)(l * 4 + 3) * FD * FD;
    const float* b0 = bs + (l * 4 + 0) * FD;
    const float* b1 = bs + (l * 4 + 1) * FD;
    const float* b2 = bs + (l * 4 + 2) * FD;
    const float* b3 = bs + (l * 4 + 3) * FD;

    gemm_dual<<<GEMM_GRID, 256, 0, stream>>>(xd, W0, dinvS + 0 * NV, hA,
                                             xs, W3, dinvS + 3 * NV, hB);
    pull2<<<PULL_GRID, 256, 0, stream>>>(
        hA, rowptr + 0 * (NV + 1), srcidx + (size_t)0 * NE, dinvD + 0 * NV,
        hB, rowptr + 3 * (NV + 1), srcidx + (size_t)3 * NE, dinvD + 3 * NV,
        b0, b3, nextd[l]);

    gemm_dual<<<GEMM_GRID, 256, 0, stream>>>(xs, W1, dinvS + 1 * NV, hA,
                                             xd, W2, dinvS + 2 * NV, hB);
    pull2<<<PULL_GRID, 256, 0, stream>>>(
        hA, rowptr + 1 * (NV + 1), srcidx + (size_t)1 * NE, dinvD + 1 * NV,
        hB, rowptr + 2 * (NV + 1), srcidx + (size_t)2 * NE, dinvD + 2 * NV,
        b1, b2, nexts[l]);

    xd = nextd[l];
    xs = nexts[l];
  }

  linear64<<<LIN_GRID, 256, 0, stream>>>(xd, lw, lb, out);
  linear64<<<LIN_GRID, 256, 0, stream>>>(xs, lw, lb, out + (size_t)NV * NOUT);
}

// Round 5
// 485.386 us; speedup vs baseline: 3.5467x; 1.3438x over previous
//
#include <hip/hip_runtime.h>

#define NV   50000
#define FD   128
#define NE   800000
#define NOUT 64
#define NBIN 196          // ceil(NV/256) coarse buckets of 256 nodes
#define CH   2048         // edges per block in P0/P1
#define NBLK 391          // ceil(NE/CH)
#define SCAN_L (NBIN * NBLK)
#define SCHUNK 2048       // elements per block in hierarchical scan
#define NSCH ((SCAN_L + SCHUNK - 1) / SCHUNK)   // 38
#define CAP2 12288        // LDS staging cap in P2 (avg span ~4083)

typedef unsigned short bf16_t;
typedef unsigned short u16;
typedef unsigned char  u8;
typedef __attribute__((ext_vector_type(8))) short bf16x8;
typedef __attribute__((ext_vector_type(4))) float f32x4;

__device__ __forceinline__ bf16_t f2bf(float f) {
  unsigned u = __builtin_bit_cast(unsigned, f);
  return (bf16_t)((u + 0x7fffu + ((u >> 16) & 1u)) >> 16);
}
__device__ __forceinline__ float bflo(unsigned v) { return __builtin_bit_cast(float, v << 16); }
__device__ __forceinline__ float bfhi(unsigned v) { return __builtin_bit_cast(float, v & 0xffff0000u); }

struct Ptr4 { const int* p[4]; };

// ================= bucket-sort based CSR build (no global atomics) =================

__global__ __launch_bounds__(256) void p0_hist(Ptr4 rows, Ptr4 cols,
                                               int* __restrict__ blockCnt) {
  const int r = blockIdx.y, blk = blockIdx.x, t = threadIdx.x;
  __shared__ int cd[NBIN], cs[NBIN];
  for (int i = t; i < NBIN; i += 256) { cd[i] = 0; cs[i] = 0; }
  __syncthreads();
  const int e0 = blk * CH;
  const int n = min(CH, NE - e0);
  const int* rw = rows.p[r] + e0;
  const int* cl = cols.p[r] + e0;
  for (int i = t; i < n; i += 256) {
    atomicAdd(&cd[cl[i] >> 8], 1);
    atomicAdd(&cs[rw[i] >> 8], 1);
  }
  __syncthreads();
  int* bd = blockCnt + (size_t)(r * 2 + 0) * SCAN_L;
  int* bs = blockCnt + (size_t)(r * 2 + 1) * SCAN_L;
  for (int i = t; i < NBIN; i += 256) {
    bd[i * NBLK + blk] = cd[i];
    bs[i * NBLK + blk] = cs[i];
  }
}

__global__ __launch_bounds__(256) void scan_pass1(const int* __restrict__ blockCnt,
                                                  int* __restrict__ chunkSum) {
  const int r2 = blockIdx.y, chunk = blockIdx.x, t = threadIdx.x;
  const int* a = blockCnt + (size_t)r2 * SCAN_L + chunk * SCHUNK;
  const int n = min(SCHUNK, SCAN_L - chunk * SCHUNK);
  int s = 0;
  for (int i = t; i < n; i += 256) s += a[i];
  __shared__ int sm[256];
  sm[t] = s;
  __syncthreads();
  #pragma unroll
  for (int off = 128; off > 0; off >>= 1) {
    if (t < off) sm[t] += sm[t + off];
    __syncthreads();
  }
  if (t == 0) chunkSum[r2 * NSCH + chunk] = sm[0];
}

__global__ __launch_bounds__(512) void scan_pass2(int* __restrict__ chunkSum,
                                                  int* __restrict__ bucketBase) {
  const int t = threadIdx.x;
  __shared__ int sm[8 * NSCH];
  if (t < 8 * NSCH) sm[t] = chunkSum[t];
  __syncthreads();
  if (t < 8) {
    int run = 0;
    for (int j = 0; j < NSCH; ++j) {
      int v = sm[t * NSCH + j];
      sm[t * NSCH + j] = run;
      run += v;
    }
    bucketBase[t * (NBIN + 1) + NBIN] = NE;
  }
  __syncthreads();
  if (t < 8 * NSCH) chunkSum[t] = sm[t];
}

__global__ __launch_bounds__(256) void scan_pass3(int* __restrict__ blockCnt,
                                                  const int* __restrict__ chunkSum,
                                                  int* __restrict__ bucketBase) {
  const int r2 = blockIdx.y, chunk = blockIdx.x, t = threadIdx.x;
  int* a = blockCnt + (size_t)r2 * SCAN_L + chunk * SCHUNK;
  const int gbase = chunk * SCHUNK;
  const int n = min(SCHUNK, SCAN_L - gbase);
  const int idx0 = t * 8;
  int v[8];
  int s = 0;
  #pragma unroll
  for (int j = 0; j < 8; ++j) {
    int id = idx0 + j;
    v[j] = (id < n) ? a[id] : 0;
    s += v[j];
  }
  __shared__ int sm[256];
  sm[t] = s;
  __syncthreads();
  for (int off = 1; off < 256; off <<= 1) {
    int x = (t >= off) ? sm[t - off] : 0;
    __syncthreads();
    sm[t] += x;
    __syncthreads();
  }
  int pre = ((t == 0) ? 0 : sm[t - 1]) + chunkSum[r2 * NSCH + chunk];
  #pragma unroll
  for (int j = 0; j < 8; ++j) {
    int id = idx0 + j;
    if (id < n) {
      int val = v[j];
      a[id] = pre;
      int g = gbase + id;
      if (g % NBLK == 0) bucketBase[r2 * (NBIN + 1) + g / NBLK] = pre;
      pre += val;
    }
  }
}

__global__ __launch_bounds__(256) void p1_scatter(Ptr4 rows, Ptr4 cols,
                                                  const int* __restrict__ blockCnt,
                                                  unsigned* __restrict__ pairD,
                                                  u8* __restrict__ srcb) {
  const int r = blockIdx.y, blk = blockIdx.x, t = threadIdx.x;
  const int e0 = blk * CH;
  const int n = min(CH, NE - e0);
  const int* rw = rows.p[r] + e0;
  const int* cl = cols.p[r] + e0;

  __shared__ int cnt[256], sc[256], lofs[256], cnt2[256], baseT[256];
  __shared__ unsigned pr[CH];
  __shared__ u8 binb[CH];
  __shared__ u8 pay8[CH];

  // ---------- dst side ----------
  cnt[t] = 0; cnt2[t] = 0;
  __syncthreads();
  for (int i = t; i < n; i += 256) atomicAdd(&cnt[cl[i] >> 8], 1);
  __syncthreads();
  sc[t] = cnt[t];
  __syncthreads();
  for (int off = 1; off < 256; off <<= 1) {
    int v = (t >= off) ? sc[t - off] : 0;
    __syncthreads();
    sc[t] += v;
    __syncthreads();
  }
  lofs[t] = (t == 0) ? 0 : sc[t - 1];
  if (t < NBIN) baseT[t] = blockCnt[(size_t)(r * 2 + 0) * SCAN_L + t * NBLK + blk];
  __syncthreads();
  for (int i = t; i < n; i += 256) {
    int c = cl[i];
    int bin = c >> 8;
    int rank = atomicAdd(&cnt2[bin], 1);
    int p = lofs[bin] + rank;
    pr[p] = ((unsigned)(c & 255) << 16) | (unsigned)rw[i];
    binb[p] = (u8)bin;
  }
  __syncthreads();
  {
    unsigned* pd = pairD + (size_t)r * NE;
    for (int i = t; i < n; i += 256) {
      int bin = binb[i];
      pd[baseT[bin] + (i - lofs[bin])] = pr[i];
    }
  }
  __syncthreads();

  // ---------- src side ----------
  cnt[t] = 0; cnt2[t] = 0;
  __syncthreads();
  for (int i = t; i < n; i += 256) atomicAdd(&cnt[rw[i] >> 8], 1);
  __syncthreads();
  sc[t] = cnt[t];
  __syncthreads();
  for (int off = 1; off < 256; off <<= 1) {
    int v = (t >= off) ? sc[t - off] : 0;
    __syncthreads();
    sc[t] += v;
    __syncthreads();
  }
  lofs[t] = (t == 0) ? 0 : sc[t - 1];
  if (t < NBIN) baseT[t] = blockCnt[(size_t)(r * 2 + 1) * SCAN_L + t * NBLK + blk];
  __syncthreads();
  for (int i = t; i < n; i += 256) {
    int sv = rw[i];
    int bin = sv >> 8;
    int rank = atomicAdd(&cnt2[bin], 1);
    int p = lofs[bin] + rank;
    pay8[p] = (u8)(sv & 255);
    binb[p] = (u8)bin;
  }
  __syncthreads();
  {
    u8* sb = srcb + (size_t)r * NE;
    for (int i = t; i < n; i += 256) {
      int bin = binb[i];
      sb[baseT[bin] + (i - lofs[bin])] = pay8[i];
    }
  }
}

__global__ __launch_bounds__(256) void p2_csr(const unsigned* __restrict__ pairD,
                                              const int* __restrict__ bucketBase,
                                              u16* __restrict__ srcidx,
                                              int* __restrict__ rowptr,
                                              float* __restrict__ dinvD) {
  const int r = blockIdx.y, bin = blockIdx.x, t = threadIdx.x;
  const int* bb = bucketBase + (r * 2 + 0) * (NBIN + 1);
  const int base = bb[bin], next = bb[bin + 1];
  const int span = next - base;
  const unsigned* pd = pairD + (size_t)r * NE + base;

  __shared__ int cnt[256], sc[256], ex[256], cnt2[256];
  __shared__ u16 lsrc[CAP2];
  cnt[t] = 0; cnt2[t] = 0;
  __syncthreads();
  for (int i = t; i < span; i += 256) atomicAdd(&cnt[pd[i] >> 16], 1);
  __syncthreads();
  sc[t] = cnt[t];
  __syncthreads();
  for (int off = 1; off < 256; off <<= 1) {
    int v = (t >= off) ? sc[t - off] : 0;
    __syncthreads();
    sc[t] += v;
    __syncthreads();
  }
  ex[t] = (t == 0) ? 0 : sc[t - 1];
  __syncthreads();

  const int node = (bin << 8) + t;
  if (node < NV) {
    rowptr[r * (NV + 1) + node] = base + ex[t];
    float deg = (float)cnt[t];
    dinvD[r * NV + node] = (r < 2) ? rsqrtf(deg + 1.f)
                                   : (deg > 0.f ? rsqrtf(deg) : 0.f);
  }
  if (bin == NBIN - 1 && t == 0) rowptr[r * (NV + 1) + NV] = NE;

  u16* so = srcidx + (size_t)r * NE + base;
  if (span <= CAP2) {
    for (int i = t; i < span; i += 256) {
      unsigned v = pd[i];
      int dl = v >> 16;
      int rank = atomicAdd(&cnt2[dl], 1);
      lsrc[ex[dl] + rank] = (u16)(v & 0xFFFFu);
    }
    __syncthreads();
    for (int i = t; i < span; i += 256) so[i] = lsrc[i];
  } else {
    for (int i = t; i < span; i += 256) {
      unsigned v = pd[i];
      int dl = v >> 16;
      int rank = atomicAdd(&cnt2[dl], 1);
      so[ex[dl] + rank] = (u16)(v & 0xFFFFu);
    }
  }
}

__global__ __launch_bounds__(256) void p2_srcdeg(const u8* __restrict__ srcb,
                                                 const int* __restrict__ bucketBase,
                                                 float* __restrict__ dinvS) {
  const int r = blockIdx.y, bin = blockIdx.x, t = threadIdx.x;
  const int* bb = bucketBase + (r * 2 + 1) * (NBIN + 1);
  const int base = bb[bin], next = bb[bin + 1];
  const int span = next - base;
  const u8* sb = srcb + (size_t)r * NE + base;
  __shared__ int cnt[256];
  cnt[t] = 0;
  __syncthreads();
  for (int i = t; i < span; i += 256) atomicAdd(&cnt[sb[i]], 1);
  __syncthreads();
  int node = (bin << 8) + t;
  if (node < NV) {
    float deg = (float)cnt[t];
    dinvS[r * NV + node] = (r < 2) ? rsqrtf(deg + 1.f)
                                   : (deg > 0.f ? rsqrtf(deg) : 0.f);
  }
}

// ================= dtype prep =================

// x fp32 -> bf16 (4 elems/thread)
__global__ __launch_bounds__(256) void xcvt(const float* __restrict__ x,
                                            bf16_t* __restrict__ xb, int n4) {
  int i = blockIdx.x * 256 + threadIdx.x;
  if (i < n4) {
    float4 v = *(const float4*)(x + (size_t)i * 4);
    unsigned a = (unsigned)f2bf(v.x) | ((unsigned)f2bf(v.y) << 16);
    unsigned b = (unsigned)f2bf(v.z) | ((unsigned)f2bf(v.w) << 16);
    *(uint2*)(xb + (size_t)i * 4) = make_uint2(a, b);
  }
}

// W[8][128k][128n] fp32 -> Wt[8][128n][128k] bf16 (transposed)
__global__ __launch_bounds__(256) void wprep(const float* __restrict__ Wsrc,
                                             bf16_t* __restrict__ Wt) {
  int idx = blockIdx.x * 256 + threadIdx.x;   // 8*128*128 = 131072
  if (idx < 8 * 128 * 128) {
    int i = idx >> 14, n = (idx >> 7) & 127, k = idx & 127;
    Wt[idx] = f2bf(Wsrc[(size_t)i * 16384 + k * 128 + n]);
  }
}

// ================= MFMA dual GEMM: H = bf16( dS * (Xb @ W) ) =================
// Xb bf16 [M,128]; Wt bf16 [128n][128k] (pre-transposed). 128-row tile, 4 waves.
__global__ __launch_bounds__(256) void gemm_mfma(
    const bf16_t* __restrict__ Xb0, const bf16_t* __restrict__ Wt0,
    const float* __restrict__ dS0, bf16_t* __restrict__ H0,
    const bf16_t* __restrict__ Xb1, const bf16_t* __restrict__ Wt1,
    const float* __restrict__ dS1, bf16_t* __restrict__ H1) {
  const bf16_t* Xb; const bf16_t* Wt; const float* dS; bf16_t* H;
  if (blockIdx.y == 0) { Xb = Xb0; Wt = Wt0; dS = dS0; H = H0; }
  else                 { Xb = Xb1; Wt = Wt1; dS = dS1; H = H1; }

  __shared__ bf16_t Xs[128][136];   // stride 272B = 68 dw -> rows offset 4 banks (2-way max)
  __shared__ bf16_t Wsh[128][136];  // Wsh[n][k]; reused as output staging after compute
  __shared__ float sdS[128];
  const int t = threadIdx.x;
  const int row0 = blockIdx.x * 128;

  #pragma unroll
  for (int j = 0; j < 8; ++j) {
    int r = (t >> 4) + j * 16;
    int c = (t & 15) * 8;
    int gr = row0 + r;
    uint4 v = make_uint4(0u, 0u, 0u, 0u);
    if (gr < NV) v = *(const uint4*)(Xb + (size_t)gr * FD + c);
    *(uint4*)&Xs[r][c] = v;
    *(uint4*)&Wsh[r][c] = *(const uint4*)(Wt + (size_t)r * FD + c);
  }
  if (t < 128) {
    int g = row0 + t;
    sdS[t] = (g < NV) ? dS[g] : 0.f;
  }
  __syncthreads();

  const int wave = t >> 6, lane = t & 63;
  const int lr = lane & 15;           // A row / B col within tile
  const int lk = (lane >> 4) * 8;     // k-slot offset
  const int mb = wave * 32;           // each wave: 2 m-tiles (32 rows)

  f32x4 acc[2][8];
  #pragma unroll
  for (int m = 0; m < 2; ++m)
    #pragma unroll
    for (int n = 0; n < 8; ++n) acc[m][n] = (f32x4){0.f, 0.f, 0.f, 0.f};

  #pragma unroll
  for (int kc = 0; kc < 128; kc += 32) {
    bf16x8 a0 = *(const bf16x8*)&Xs[mb + lr][kc + lk];
    bf16x8 a1 = *(const bf16x8*)&Xs[mb + 16 + lr][kc + lk];
    bf16x8 b[8];
    #pragma unroll
    for (int n = 0; n < 8; ++n) b[n] = *(const bf16x8*)&Wsh[n * 16 + lr][kc + lk];
    #pragma unroll
    for (int n = 0; n < 8; ++n) {
      acc[0][n] = __builtin_amdgcn_mfma_f32_16x16x32_bf16(a0, b[n], acc[0][n], 0, 0, 0);
      acc[1][n] = __builtin_amdgcn_mfma_f32_16x16x32_bf16(a1, b[n], acc[1][n], 0, 0, 0);
    }
  }

  __syncthreads();   // done reading Wsh; reuse as bf16 output staging
  const int rgrp = (lane >> 4) * 4;
  #pragma unroll
  for (int m = 0; m < 2; ++m)
    #pragma unroll
    for (int n = 0; n < 8; ++n)
      #pragma unroll
      for (int j = 0; j < 4; ++j) {
        int rr = mb + m * 16 + rgrp + j;
        Wsh[rr][n * 16 + lr] = f2bf(acc[m][n][j] * sdS[rr]);
      }
  __syncthreads();

  #pragma unroll
  for (int j = 0; j < 8; ++j) {
    int r = (t >> 4) + j * 16;
    int c = (t & 15) * 8;
    int gr = row0 + r;
    if (gr < NV) *(uint4*)(H + (size_t)gr * FD + c) = *(const uint4*)&Wsh[r][c];
  }
}

// ================= fused pull aggregation (bf16 in, bf16 out) =================
__device__ __forceinline__ void gather_acc(const bf16_t* __restrict__ h,
                                           const u16* __restrict__ src,
                                           int p0, int p1, int d,
                                           float& ax, float& ay) {
  int p = p0;
  for (; p + 4 <= p1; p += 4) {
    int s0 = src[p], s1 = src[p + 1], s2 = src[p + 2], s3 = src[p + 3];
    unsigned v0 = *(const unsigned*)(h + ((size_t)s0 << 7) + d);
    unsigned v1 = *(const unsigned*)(h + ((size_t)s1 << 7) + d);
    unsigned v2 = *(const unsigned*)(h + ((size_t)s2 << 7) + d);
    unsigned v3 = *(const unsigned*)(h + ((size_t)s3 << 7) + d);
    ax += bflo(v0); ay += bfhi(v0);
    ax += bflo(v1); ay += bfhi(v1);
    ax += bflo(v2); ay += bfhi(v2);
    ax += bflo(v3); ay += bfhi(v3);
  }
  for (; p < p1; ++p) {
    int s = src[p];
    unsigned v = *(const unsigned*)(h + ((size_t)s << 7) + d);
    ax += bflo(v); ay += bfhi(v);
  }
}

__global__ __launch_bounds__(256) void pull2(
    const bf16_t* __restrict__ hA, const int* __restrict__ rpA, const u16* __restrict__ srcA,
    const float* __restrict__ dDA,
    const bf16_t* __restrict__ hB, const int* __restrict__ rpB, const u16* __restrict__ srcB,
    const float* __restrict__ dDB,
    const float* __restrict__ bA, const float* __restrict__ bB,
    bf16_t* __restrict__ Y) {
  const int i = (blockIdx.x * 256 + threadIdx.x) >> 6;
  const int lane = threadIdx.x & 63;
  if (i >= NV) return;
  const int d = lane * 2;

  float ax, ay;
  {
    unsigned v = *(const unsigned*)(hA + ((size_t)i << 7) + d);
    ax = bflo(v); ay = bfhi(v);
  }
  gather_acc(hA, srcA, rpA[i], rpA[i + 1], d, ax, ay);
  float bx = 0.f, by = 0.f;
  gather_acc(hB, srcB, rpB[i], rpB[i + 1], d, bx, by);

  float wA = dDA[i], wB = dDB[i];
  float ox = fmaf(ax, wA, fmaf(bx, wB, bA[d] + bB[d]));
  float oy = fmaf(ay, wA, fmaf(by, wB, bA[d + 1] + bB[d + 1]));
  unsigned pk = (unsigned)f2bf(fmaxf(ox, 0.f)) | ((unsigned)f2bf(fmaxf(oy, 0.f)) << 16);
  *(unsigned*)(Y + (size_t)i * FD + d) = pk;
}

// ================= final linear: Out[NV,64] = X[NV,128] @ lw^T + lb =================
__global__ __launch_bounds__(256) void linear64(const bf16_t* __restrict__ Xb,
                                                const float* __restrict__ lw,
                                                const float* __restrict__ lb,
                                                float* __restrict__ Out) {
  __shared__ float Wt[128][68];
  __shared__ float Xs[64][132];
  const int tid = threadIdx.x;
  const int row0 = blockIdx.x * 64;

  for (int i = tid * 4; i < 64 * 128; i += 1024) {
    float4 v = *(const float4*)(lw + i);
    int o = i >> 7, h = i & 127;
    Wt[h + 0][o] = v.x; Wt[h + 1][o] = v.y; Wt[h + 2][o] = v.z; Wt[h + 3][o] = v.w;
  }
  for (int i = tid * 8; i < 64 * 128; i += 2048) {
    int rr = i >> 7, cc = i & 127;
    int gr = row0 + rr;
    uint4 v = make_uint4(0u, 0u, 0u, 0u);
    if (gr < NV) v = *(const uint4*)(Xb + (size_t)gr * FD + cc);
    unsigned* pv = (unsigned*)&v;
    #pragma unroll
    for (int q = 0; q < 4; ++q) {
      Xs[rr][cc + q * 2]     = bflo(pv[q]);
      Xs[rr][cc + q * 2 + 1] = bfhi(pv[q]);
    }
  }
  __syncthreads();

  const int tx = tid & 15, ty = tid >> 4;
  float acc[4][4];
  #pragma unroll
  for (int i = 0; i < 4; ++i)
    #pragma unroll
    for (int j = 0; j < 4; ++j) acc[i][j] = 0.f;

  for (int k = 0; k < 128; k += 4) {
    float4 xr[4], w[4];
    #pragma unroll
    for (int i = 0; i < 4; ++i) xr[i] = *(const float4*)&Xs[ty * 4 + i][k];
    #pragma unroll
    for (int j = 0; j < 4; ++j) w[j] = *(const float4*)&Wt[k + j][tx * 4];
    #pragma unroll
    for (int i = 0; i < 4; ++i) {
      const float* xv = (const float*)&xr[i];
      #pragma unroll
      for (int j = 0; j < 4; ++j) {
        float x = xv[j];
        acc[i][0] = fmaf(x, w[j].x, acc[i][0]);
        acc[i][1] = fmaf(x, w[j].y, acc[i][1]);
        acc[i][2] = fmaf(x, w[j].z, acc[i][2]);
        acc[i][3] = fmaf(x, w[j].w, acc[i][3]);
      }
    }
  }
  float4 bias = *(const float4*)(lb + tx * 4);
  #pragma unroll
  for (int i = 0; i < 4; ++i) {
    int gr = row0 + ty * 4 + i;
    if (gr < NV) {
      *(float4*)(Out + (size_t)gr * NOUT + tx * 4) =
          make_float4(acc[i][0] + bias.x, acc[i][1] + bias.y,
                      acc[i][2] + bias.z, acc[i][3] + bias.w);
    }
  }
}

// ================= host orchestration =================

extern "C" void kernel_launch(void* const* d_in, const int* in_sizes, int n_in,
                              void* d_out, int out_size, void* d_ws, size_t ws_size,
                              hipStream_t stream) {
  const float* x_drug = (const float*)d_in[0];
  const float* x_dis  = (const float*)d_in[1];
  const int* ei[4] = { (const int*)d_in[2], (const int*)d_in[3],
                       (const int*)d_in[4], (const int*)d_in[5] };  // dd, ss, ds, sd
  const float* Ws = (const float*)d_in[6];
  const float* bs = (const float*)d_in[7];
  const float* lw = (const float*)d_in[8];
  const float* lb = (const float*)d_in[9];
  float* out = (float*)d_out;

  char* p = (char*)d_ws;
  auto take = [&](size_t bytes) -> void* {
    char* q = p;
    p += (bytes + 255) & ~(size_t)255;
    return (void*)q;
  };
  int* blockCnt   = (int*)take((size_t)8 * SCAN_L * sizeof(int));
  int* chunkSum   = (int*)take((size_t)8 * NSCH * sizeof(int));
  int* bucketBase = (int*)take((size_t)8 * (NBIN + 1) * sizeof(int));
  unsigned* pairD = (unsigned*)take((size_t)4 * NE * sizeof(unsigned));
  u8* srcb        = (u8*)take((size_t)4 * NE);
  u16* srcidx     = (u16*)take((size_t)4 * NE * sizeof(u16));
  int* rowptr     = (int*)take((size_t)4 * (NV + 1) * sizeof(int));
  float* dinvS    = (float*)take((size_t)4 * NV * sizeof(float));
  float* dinvD    = (float*)take((size_t)4 * NV * sizeof(float));
  bf16_t* hA  = (bf16_t*)take((size_t)NV * FD * sizeof(bf16_t));
  bf16_t* hB  = (bf16_t*)take((size_t)NV * FD * sizeof(bf16_t));
  bf16_t* xdb = (bf16_t*)take((size_t)NV * FD * sizeof(bf16_t));
  bf16_t* xsb = (bf16_t*)take((size_t)NV * FD * sizeof(bf16_t));
  bf16_t* Wtb = (bf16_t*)take((size_t)8 * FD * FD * sizeof(bf16_t));
  bf16_t* XD1 = (bf16_t*)take((size_t)NV * FD * sizeof(bf16_t));
  bf16_t* XS1 = (bf16_t*)take((size_t)NV * FD * sizeof(bf16_t));
  bf16_t* XD2 = (bf16_t*)take((size_t)NV * FD * sizeof(bf16_t));
  bf16_t* XS2 = (bf16_t*)take((size_t)NV * FD * sizeof(bf16_t));

  Ptr4 rows = {{ ei[0], ei[1], ei[2], ei[3] }};
  Ptr4 cols = {{ ei[0] + NE, ei[1] + NE, ei[2] + NE, ei[3] + NE }};

  // ---- prep ----
  p0_hist<<<dim3(NBLK, 4), 256, 0, stream>>>(rows, cols, blockCnt);
  scan_pass1<<<dim3(NSCH, 8), 256, 0, stream>>>(blockCnt, chunkSum);
  scan_pass2<<<1, 512, 0, stream>>>(chunkSum, bucketBase);
  scan_pass3<<<dim3(NSCH, 8), 256, 0, stream>>>(blockCnt, chunkSum, bucketBase);
  p1_scatter<<<dim3(NBLK, 4), 256, 0, stream>>>(rows, cols, blockCnt, pairD, srcb);
  p2_csr<<<dim3(NBIN, 4), 256, 0, stream>>>(pairD, bucketBase, srcidx, rowptr, dinvD);
  p2_srcdeg<<<dim3(NBIN, 4), 256, 0, stream>>>(srcb, bucketBase, dinvS);
  xcvt<<<(NV * FD / 4 + 255) / 256, 256, 0, stream>>>(x_drug, xdb, NV * FD / 4);
  xcvt<<<(NV * FD / 4 + 255) / 256, 256, 0, stream>>>(x_dis, xsb, NV * FD / 4);
  wprep<<<(8 * FD * FD + 255) / 256, 256, 0, stream>>>(Ws, Wtb);

  // ---- layers ----
  const dim3 GEMM_GRID((NV + 127) / 128, 2);
  const int PULL_GRID = NV * 64 / 256;
  const int LIN_GRID = (NV + 63) / 64;
  const bf16_t* xd = xdb;
  const bf16_t* xs = xsb;
  bf16_t* nextd[2] = {XD1, XD2};
  bf16_t* nexts[2] = {XS1, XS2};
  for (int l = 0; l < 2; ++l) {
    const bf16_t* W0 = Wtb + (size_t)(l * 4 + 0) * FD * FD;
    const bf16_t* W1 = Wtb + (size_t)(l * 4 + 1) * FD * FD;
    const bf16_t* W2 = Wtb + (size_t)(l * 4 + 2) * FD * FD;
    const bf16_t* W3 = Wtb + (size_t)(l * 4 + 3) * FD * FD;
    const float* b0 = bs + (l * 4 + 0) * FD;
    const float* b1 = bs + (l * 4 + 1) * FD;
    const float* b2 = bs + (l * 4 + 2) * FD;
    const float* b3 = bs + (l * 4 + 3) * FD;

    gemm_mfma<<<GEMM_GRID, 256, 0, stream>>>(xd, W0, dinvS + 0 * NV, hA,
                                             xs, W3, dinvS + 3 * NV, hB);
    pull2<<<PULL_GRID, 256, 0, stream>>>(
        hA, rowptr + 0 * (NV + 1), srcidx + (size_t)0 * NE, dinvD + 0 * NV,
        hB, rowptr + 3 * (NV + 1), srcidx + (size_t)3 * NE, dinvD + 3 * NV,
        b0, b3, nextd[l]);

    gemm_mfma<<<GEMM_GRID, 256, 0, stream>>>(xs, W1, dinvS + 1 * NV, hA,
                                             xd, W2, dinvS + 2 * NV, hB);
    pull2<<<PULL_GRID, 256, 0, stream>>>(
        hA, rowptr + 1 * (NV + 1), srcidx + (size_t)1 * NE, dinvD + 1 * NV,
        hB, rowptr + 2 * (NV + 1), srcidx + (size_t)2 * NE, dinvD + 2 * NV,
        b1, b2, nexts[l]);

    xd = nextd[l];
    xs = nexts[l];
  }

  linear64<<<LIN_GRID, 256, 0, stream>>>(xd, lw, lb, out);
  linear64<<<LIN_GRID, 256, 0, stream>>>(xs, lw, lb, out + (size_t)NV * NOUT);
}